// Round 1
// baseline (755.646 us; speedup 1.0000x reference)
//
#include <hip/hip_runtime.h>

typedef unsigned short u16;
typedef __bf16 bfx8 __attribute__((ext_vector_type(8)));
typedef float f32x4 __attribute__((ext_vector_type(4)));
typedef unsigned short u16x4 __attribute__((ext_vector_type(4)));

#define NN 1024
#define FF 64
#define NSLICE 32
#define KFEAT 11

// ---- workspace layout ----
// [0, POOL_BYTES)            pooled accumulators (f32, zeroed each call)
// [POOL_BYTES, +128)         msum per slice
// [SLICE0 + s*PS_BYTES ...)  per-slice chunk regions
#define POOL_BYTES (NSLICE * KFEAT * FF * 4)  // 90112
#define MSUM_OFF   POOL_BYTES
#define SLICE0     ((size_t)1 << 20)
#define MB2        (2u * 1024u * 1024u)
#define OFF_R0     0u
#define OFF_R1     (1u * MB2)
#define OFF_R2     (2u * MB2)
#define OFF_T      (3u * MB2)
#define OFF_PSI0   (4u * MB2)
#define OFF_PSI1   (5u * MB2)
#define OFF_PSI2   (6u * MB2)
#define OFF_XT     (7u * MB2)                    // 128KB  bf16 [64][1024]
#define OFF_SCT    (7u * MB2 + 131072u)          // 4x128KB bf16 [64][1024]
#define OFF_U      (7u * MB2 + 131072u * 5u)     // 256KB  f32 [1024][64]
#define OFF_UT     (7u * MB2 + 131072u * 7u)     // 128KB  bf16 [64][1024]
#define PS_BYTES   ((size_t)(7u * MB2 + 131072u * 8u))  // 15728640

__device__ __forceinline__ u16 f2b(float v) {
  __bf16 h = (__bf16)v;
  return __builtin_bit_cast(u16, h);
}
__device__ __forceinline__ float b2f(u16 u) {
  return (float)__builtin_bit_cast(__bf16, u);
}

// ---- P slice: f32 -> bf16 row-major (R0) + bf16 transposed (T) ----
__global__ void k_convP(const float* __restrict__ P, char* ws, int sliceBase) {
  __shared__ float tile[64][65];
  int s = blockIdx.z;
  const float* Ps = P + (size_t)(sliceBase + s) * NN * NN;
  char* base = ws + SLICE0 + (size_t)s * PS_BYTES;
  u16* Pb  = (u16*)(base + OFF_R0);
  u16* PbT = (u16*)(base + OFF_T);
  int r0 = blockIdx.y * 64, c0 = blockIdx.x * 64;
  int tx = threadIdx.x & 63, ty = threadIdx.x >> 6;
  for (int rr = 0; rr < 64; rr += 4) {
    float v = Ps[(size_t)(r0 + rr + ty) * NN + c0 + tx];
    tile[rr + ty][tx] = v;
    Pb[(size_t)(r0 + rr + ty) * NN + c0 + tx] = f2b(v);
  }
  __syncthreads();
  for (int rr = 0; rr < 64; rr += 4)
    PbT[(size_t)(c0 + rr + ty) * NN + r0 + tx] = f2b(tile[tx][rr + ty]);
}

// ---- X slice: f32 [1024][64] -> bf16 XT [64][1024] ----
__global__ void k_convX(const float* __restrict__ X, char* ws, int sliceBase) {
  __shared__ float tile[64][65];
  int s = blockIdx.z;
  const float* Xs = X + (size_t)(sliceBase + s) * NN * FF;
  u16* XT = (u16*)(ws + SLICE0 + (size_t)s * PS_BYTES + OFF_XT);
  int r0 = blockIdx.x * 64;
  int tx = threadIdx.x & 63, ty = threadIdx.x >> 6;
  for (int rr = 0; rr < 64; rr += 4)
    tile[rr + ty][tx] = Xs[(size_t)(r0 + rr + ty) * FF + tx];
  __syncthreads();
  for (int rr = 0; rr < 64; rr += 4)
    XT[(size_t)(rr + ty) * NN + r0 + tx] = f2b(tile[tx][rr + ty]);
}

// ---- bf16 [1024][1024] transpose (row buffer -> T buffer) ----
__global__ void k_transp(char* ws, int offIn, int offOut) {
  __shared__ u16 tile[64][66];
  char* base = ws + SLICE0 + (size_t)blockIdx.z * PS_BYTES;
  const u16* In = (const u16*)(base + offIn);
  u16* Out = (u16*)(base + offOut);
  int r0 = blockIdx.y * 64, c0 = blockIdx.x * 64;
  int tx = threadIdx.x & 63, ty = threadIdx.x >> 6;
  for (int rr = 0; rr < 64; rr += 4)
    tile[rr + ty][tx] = In[(size_t)(r0 + rr + ty) * NN + c0 + tx];
  __syncthreads();
  for (int rr = 0; rr < 64; rr += 4)
    Out[(size_t)(c0 + rr + ty) * NN + r0 + tx] = tile[tx][rr + ty];
}

__global__ void k_msum(const float* __restrict__ mask, float* msum) {
  int s = blockIdx.x;
  const float* m = mask + (size_t)s * NN;
  int t = threadIdx.x;
  float v = m[t] + m[t + 256] + m[t + 512] + m[t + 768];
  for (int o = 32; o; o >>= 1) v += __shfl_down(v, o);
  __shared__ float ps[4];
  if ((t & 63) == 0) ps[t >> 6] = v;
  __syncthreads();
  if (t == 0) msum[s] = ps[0] + ps[1] + ps[2] + ps[3];
}

// ---- squaring GEMM: C = A @ B (B given transposed). Writes newP bf16 and
// psi = newP - oldP (f32 subtract, bf16 store). 128x128 tile, BK=32, 4 waves.
__global__ __launch_bounds__(256, 2)
void k_square(char* ws, int offA, int offB, int offC, int offOld, int offPsi) {
  char* base = ws + SLICE0 + (size_t)blockIdx.z * PS_BYTES;
  const u16* A   = (const u16*)(base + offA);
  const u16* Bt  = (const u16*)(base + offB);
  u16* C         = (u16*)(base + offC);
  const u16* Old = (const u16*)(base + offOld);
  u16* Psi       = (u16*)(base + offPsi);

  __shared__ u16 lA[128 * 32];
  __shared__ u16 lB[128 * 32];
  const int tid = threadIdx.x;
  const int lane = tid & 63, wave = tid >> 6;
  const int wr = wave >> 1, wc = wave & 1;
  const int l16 = lane & 15, lk = lane >> 4;
  const int bm = blockIdx.y * 128, bn = blockIdx.x * 128;

  const int srow = tid >> 2, skk = (tid & 3) << 3;
  const u16* gA = A + (size_t)(bm + srow) * NN + skk;
  const u16* gB = Bt + (size_t)(bn + srow) * NN + skk;

  f32x4 acc[4][4] = {};

  for (int k0 = 0; k0 < NN; k0 += 32) {
    uint4 ra0 = *(const uint4*)(gA + k0);
    uint4 ra1 = *(const uint4*)(gA + 64 * NN + k0);
    uint4 rb0 = *(const uint4*)(gB + k0);
    uint4 rb1 = *(const uint4*)(gB + 64 * NN + k0);
    __syncthreads();
    ((uint4*)lA)[tid] = ra0;
    ((uint4*)lA)[tid + 256] = ra1;
    ((uint4*)lB)[tid] = rb0;
    ((uint4*)lB)[tid + 256] = rb1;
    __syncthreads();
    bfx8 af[4], bfr[4];
#pragma unroll
    for (int m = 0; m < 4; ++m)
      af[m] = *(const bfx8*)&lA[(wr * 64 + m * 16 + l16) * 32 + lk * 8];
#pragma unroll
    for (int n = 0; n < 4; ++n)
      bfr[n] = *(const bfx8*)&lB[(wc * 64 + n * 16 + l16) * 32 + lk * 8];
#pragma unroll
    for (int m = 0; m < 4; ++m)
#pragma unroll
      for (int n = 0; n < 4; ++n)
        acc[m][n] = __builtin_amdgcn_mfma_f32_16x16x32_bf16(af[m], bfr[n], acc[m][n], 0, 0, 0);
  }

#pragma unroll
  for (int m = 0; m < 4; ++m) {
    int row0 = bm + wr * 64 + m * 16 + lk * 4;
#pragma unroll
    for (int n = 0; n < 4; ++n) {
      int col = bn + wc * 64 + n * 16 + l16;
#pragma unroll
      for (int r = 0; r < 4; ++r) {
        size_t idx = (size_t)(row0 + r) * NN + col;
        float v = acc[m][n][r];
        C[idx] = f2b(v);
        Psi[idx] = f2b(v - b2f(Old[idx]));
      }
    }
  }
}

// ---- feature GEMM: [1024x64] = A[1024x1024] @ B (Bt [64][1024]).
// V=0: A=psi_sub, B=XT  -> scT_sub + pool(1+sub)
// V=1: A=P8,      B=XT  -> U (f32) + UT
// V=2: A=P8,      B=UT  -> pool F0 (k=0); sc3=|acc-U| -> scT3 + pool(4)
// V=3: A=psi_j,   B=scT_i -> pool(5+pair)
template <int V>
__global__ __launch_bounds__(256, 2)
void k_feat(char* ws, int sliceBase, float* __restrict__ pooled) {
  int z = blockIdx.z;
  int s, sub;
  if (V == 0)      { s = z / 3; sub = z % 3; }
  else if (V == 3) { s = z / 6; sub = z % 6; }
  else             { s = z;     sub = 0;     }
  char* base = ws + SLICE0 + (size_t)s * PS_BYTES;

  const u16* A;
  const u16* Bt;
  int kidx = 0;
  if (V == 0) {
    A = (const u16*)(base + OFF_PSI0 + (size_t)sub * MB2);
    Bt = (const u16*)(base + OFF_XT);
    kidx = 1 + sub;
  } else if (V == 1) {
    A = (const u16*)(base + OFF_R0);
    Bt = (const u16*)(base + OFF_XT);
  } else if (V == 2) {
    A = (const u16*)(base + OFF_R0);
    Bt = (const u16*)(base + OFF_UT);
  } else {
    const int jj[6] = {0, 0, 1, 0, 1, 2};
    const int ii[6] = {1, 2, 2, 3, 3, 3};
    A = (const u16*)(base + OFF_PSI0 + (size_t)jj[sub] * MB2);
    Bt = (const u16*)(base + OFF_SCT + (size_t)ii[sub] * 131072u);
    kidx = 5 + sub;
  }
  float* U = (float*)(base + OFF_U);
  u16* UT = (u16*)(base + OFF_UT);
  u16* scT = (u16*)(base + OFF_SCT + (size_t)(V == 0 ? sub : 3) * 131072u);
  int poolBase = (sliceBase + s) * (KFEAT * FF);

  __shared__ u16 lA[128 * 32];
  __shared__ u16 lB[64 * 32];
  const int tid = threadIdx.x;
  const int lane = tid & 63, wave = tid >> 6;
  const int wr = wave >> 1, wc = wave & 1;
  const int l16 = lane & 15, lk = lane >> 4;
  const int bm = blockIdx.y * 128;

  const int srow = tid >> 2, skk = (tid & 3) << 3;
  const u16* gA = A + (size_t)(bm + srow) * NN + skk;
  const u16* gB = Bt + (size_t)srow * NN + skk;

  f32x4 acc[4][2] = {};
  for (int k0 = 0; k0 < NN; k0 += 32) {
    uint4 ra0 = *(const uint4*)(gA + k0);
    uint4 ra1 = *(const uint4*)(gA + 64 * NN + k0);
    uint4 rb0 = *(const uint4*)(gB + k0);
    __syncthreads();
    ((uint4*)lA)[tid] = ra0;
    ((uint4*)lA)[tid + 256] = ra1;
    ((uint4*)lB)[tid] = rb0;
    __syncthreads();
    bfx8 af[4], bfr[2];
#pragma unroll
    for (int m = 0; m < 4; ++m)
      af[m] = *(const bfx8*)&lA[(wr * 64 + m * 16 + l16) * 32 + lk * 8];
#pragma unroll
    for (int n = 0; n < 2; ++n)
      bfr[n] = *(const bfx8*)&lB[(wc * 32 + n * 16 + l16) * 32 + lk * 8];
#pragma unroll
    for (int m = 0; m < 4; ++m)
#pragma unroll
      for (int n = 0; n < 2; ++n)
        acc[m][n] = __builtin_amdgcn_mfma_f32_16x16x32_bf16(af[m], bfr[n], acc[m][n], 0, 0, 0);
  }

  float ps[2] = {0.f, 0.f};
  float psF0[2] = {0.f, 0.f};

#pragma unroll
  for (int m = 0; m < 4; ++m) {
    int row0 = bm + wr * 64 + m * 16 + lk * 4;
#pragma unroll
    for (int n = 0; n < 2; ++n) {
      int col = wc * 32 + n * 16 + l16;
      float v0 = acc[m][n][0], v1 = acc[m][n][1], v2 = acc[m][n][2], v3 = acc[m][n][3];
      if (V == 0 || V == 3) {
        v0 = fabsf(v0); v1 = fabsf(v1); v2 = fabsf(v2); v3 = fabsf(v3);
        ps[n] += v0 + v1 + v2 + v3;
        if (V == 0) {
          u16x4 pk = {f2b(v0), f2b(v1), f2b(v2), f2b(v3)};
          *(u16x4*)&scT[(size_t)col * NN + row0] = pk;
        }
      } else if (V == 1) {
        U[(size_t)(row0 + 0) * FF + col] = v0;
        U[(size_t)(row0 + 1) * FF + col] = v1;
        U[(size_t)(row0 + 2) * FF + col] = v2;
        U[(size_t)(row0 + 3) * FF + col] = v3;
        u16x4 pk = {f2b(v0), f2b(v1), f2b(v2), f2b(v3)};
        *(u16x4*)&UT[(size_t)col * NN + row0] = pk;
      } else {  // V == 2
        psF0[n] += v0 + v1 + v2 + v3;
        float u0 = U[(size_t)(row0 + 0) * FF + col];
        float u1 = U[(size_t)(row0 + 1) * FF + col];
        float u2 = U[(size_t)(row0 + 2) * FF + col];
        float u3 = U[(size_t)(row0 + 3) * FF + col];
        float d0 = fabsf(v0 - u0), d1 = fabsf(v1 - u1);
        float d2 = fabsf(v2 - u2), d3 = fabsf(v3 - u3);
        ps[n] += d0 + d1 + d2 + d3;
        u16x4 pk = {f2b(d0), f2b(d1), f2b(d2), f2b(d3)};
        *(u16x4*)&scT[(size_t)col * NN + row0] = pk;
      }
    }
  }

  if (V != 1) {
#pragma unroll
    for (int n = 0; n < 2; ++n) {
      float v = ps[n];
      v += __shfl_xor(v, 16);
      v += __shfl_xor(v, 32);
      if (lane < 16) {
        int kk = (V == 2) ? 4 : kidx;
        atomicAdd(&pooled[poolBase + kk * FF + wc * 32 + n * 16 + lane], v);
      }
      if (V == 2) {
        float f = psF0[n];
        f += __shfl_xor(f, 16);
        f += __shfl_xor(f, 32);
        if (lane < 16)
          atomicAdd(&pooled[poolBase + 0 * FF + wc * 32 + n * 16 + lane], f);
      }
    }
  }
}

__global__ void k_final(const float* __restrict__ pooled, const float* __restrict__ msum,
                        float* __restrict__ out, int total) {
  int i = blockIdx.x * 256 + threadIdx.x;
  if (i < total) out[i] = pooled[i] / msum[i / (KFEAT * FF)];
}

extern "C" void kernel_launch(void* const* d_in, const int* in_sizes, int n_in,
                              void* d_out, int out_size, void* d_ws, size_t ws_size,
                              hipStream_t stream) {
  const float* P = (const float*)d_in[0];
  const float* X = (const float*)d_in[1];
  const float* mask = (const float*)d_in[2];
  float* out = (float*)d_out;
  char* ws = (char*)d_ws;
  float* pooled = (float*)ws;
  float* msum = (float*)(ws + MSUM_OFF);

  hipMemsetAsync(pooled, 0, POOL_BYTES, stream);
  k_msum<<<NSLICE, 256, 0, stream>>>(mask, msum);

  // chunk slices to fit workspace (15 MB per slice + 1 MB header)
  int S = 1;
  if (ws_size > SLICE0 + PS_BYTES) S = (int)((ws_size - SLICE0) / PS_BYTES);
  if (S > NSLICE) S = NSLICE;
  if (S < 1) S = 1;

  for (int b0 = 0; b0 < NSLICE; b0 += S) {
    int n = (NSLICE - b0 < S) ? (NSLICE - b0) : S;
    k_convP<<<dim3(16, 16, n), 256, 0, stream>>>(P, ws, b0);
    k_convX<<<dim3(16, 1, n), 256, 0, stream>>>(X, ws, b0);
    // P2 = Pb@Pb -> R1, psi0 = P2 - Pb
    k_square<<<dim3(8, 8, n), 256, 0, stream>>>(ws, OFF_R0, OFF_T, OFF_R1, OFF_R0, OFF_PSI0);
    k_transp<<<dim3(16, 16, n), 256, 0, stream>>>(ws, OFF_R1, OFF_T);
    // P4 = P2@P2 -> R2, psi1 = P4 - P2
    k_square<<<dim3(8, 8, n), 256, 0, stream>>>(ws, OFF_R1, OFF_T, OFF_R2, OFF_R1, OFF_PSI1);
    k_transp<<<dim3(16, 16, n), 256, 0, stream>>>(ws, OFF_R2, OFF_T);
    // P8 = P4@P4 -> R0, psi2 = P8 - P4
    k_square<<<dim3(8, 8, n), 256, 0, stream>>>(ws, OFF_R2, OFF_T, OFF_R0, OFF_R2, OFF_PSI2);
    // sc_i = |psi_i X|, i=0..2 ; U = P8 X ; V = P8 U (F0 + sc3) ; F2 pairs
    k_feat<0><<<dim3(1, 8, n * 3), 256, 0, stream>>>(ws, b0, pooled);
    k_feat<1><<<dim3(1, 8, n), 256, 0, stream>>>(ws, b0, pooled);
    k_feat<2><<<dim3(1, 8, n), 256, 0, stream>>>(ws, b0, pooled);
    k_feat<3><<<dim3(1, 8, n * 6), 256, 0, stream>>>(ws, b0, pooled);
  }
  int total = NSLICE * KFEAT * FF;
  k_final<<<(total + 255) / 256, 256, 0, stream>>>(pooled, msum, out, total);
}

// Round 2
// 676.068 us; speedup vs baseline: 1.1177x; 1.1177x over previous
//
#include <hip/hip_runtime.h>

typedef unsigned short u16;
typedef __bf16 bfx8 __attribute__((ext_vector_type(8)));
typedef float f32x4 __attribute__((ext_vector_type(4)));
typedef unsigned short u16x4 __attribute__((ext_vector_type(4)));

#define NN 1024
#define FF 64
#define NSLICE 32
#define KFEAT 11

// ---- workspace layout ----
#define POOL_BYTES (NSLICE * KFEAT * FF * 4)  // 90112
#define MSUM_OFF   POOL_BYTES
#define SLICE0     ((size_t)1 << 20)
#define MB2        (2u * 1024u * 1024u)
#define OFF_R0     0u
#define OFF_R1     (1u * MB2)
#define OFF_R2     (2u * MB2)
#define OFF_T      (3u * MB2)
#define OFF_PSI0   (4u * MB2)
#define OFF_PSI1   (5u * MB2)
#define OFF_PSI2   (6u * MB2)
#define OFF_XT     (7u * MB2)                    // 128KB  bf16 [64][1024]
#define OFF_SCT    (7u * MB2 + 131072u)          // 4x128KB bf16 [64][1024]
#define OFF_U      (7u * MB2 + 131072u * 5u)     // 256KB  f32 [1024][64]
#define OFF_UT     (7u * MB2 + 131072u * 7u)     // 128KB  bf16 [64][1024]
#define PS_BYTES   ((size_t)(7u * MB2 + 131072u * 8u))  // 15728640

// async global->LDS, 16B per lane; LDS dest = wave-uniform base + lane*16
#define GL16(g, l) __builtin_amdgcn_global_load_lds( \
    (const __attribute__((address_space(1))) unsigned int*)(g), \
    (__attribute__((address_space(3))) unsigned int*)(l), 16, 0, 0)

__device__ __forceinline__ u16 f2b(float v) {
  __bf16 h = (__bf16)v;
  return __builtin_bit_cast(u16, h);
}
__device__ __forceinline__ float b2f(u16 u) {
  return (float)__builtin_bit_cast(__bf16, u);
}

// ---- P slice: f32 -> bf16 row-major (R0) + bf16 transposed (T) ----
__global__ void k_convP(const float* __restrict__ P, char* ws, int sliceBase) {
  __shared__ float tile[64][65];
  int s = blockIdx.z;
  const float* Ps = P + (size_t)(sliceBase + s) * NN * NN;
  char* base = ws + SLICE0 + (size_t)s * PS_BYTES;
  u16* Pb  = (u16*)(base + OFF_R0);
  u16* PbT = (u16*)(base + OFF_T);
  int r0 = blockIdx.y * 64, c0 = blockIdx.x * 64;
  int tid = threadIdx.x;
  int tc = tid & 15, tr = tid >> 4;  // 16 rows per iter, float4 per lane
  for (int rr = 0; rr < 64; rr += 16) {
    int r = rr + tr;
    float4 v = *(const float4*)&Ps[(size_t)(r0 + r) * NN + c0 + tc * 4];
    tile[r][tc * 4 + 0] = v.x;
    tile[r][tc * 4 + 1] = v.y;
    tile[r][tc * 4 + 2] = v.z;
    tile[r][tc * 4 + 3] = v.w;
    u16x4 pk = {f2b(v.x), f2b(v.y), f2b(v.z), f2b(v.w)};
    *(u16x4*)&Pb[(size_t)(r0 + r) * NN + c0 + tc * 4] = pk;
  }
  __syncthreads();
  // transposed: per iter 16 out-rows (src cols), 16 chunks of 4 src-rows
  for (int it = 0; it < 4; ++it) {
    int oc = (tid >> 4) + it * 16;  // src col = out row
    int ch = tid & 15;              // 4-src-row chunk
    u16x4 pk = {f2b(tile[ch * 4 + 0][oc]), f2b(tile[ch * 4 + 1][oc]),
                f2b(tile[ch * 4 + 2][oc]), f2b(tile[ch * 4 + 3][oc])};
    *(u16x4*)&PbT[(size_t)(c0 + oc) * NN + r0 + ch * 4] = pk;
  }
}

// ---- X slice: f32 [1024][64] -> bf16 XT [64][1024] ----
__global__ void k_convX(const float* __restrict__ X, char* ws, int sliceBase) {
  __shared__ float tile[64][65];
  int s = blockIdx.z;
  const float* Xs = X + (size_t)(sliceBase + s) * NN * FF;
  u16* XT = (u16*)(ws + SLICE0 + (size_t)s * PS_BYTES + OFF_XT);
  int r0 = blockIdx.x * 64;
  int tx = threadIdx.x & 63, ty = threadIdx.x >> 6;
  for (int rr = 0; rr < 64; rr += 4)
    tile[rr + ty][tx] = Xs[(size_t)(r0 + rr + ty) * FF + tx];
  __syncthreads();
  for (int rr = 0; rr < 64; rr += 4)
    XT[(size_t)(rr + ty) * NN + r0 + tx] = f2b(tile[tx][rr + ty]);
}

__global__ void k_msum(const float* __restrict__ mask, float* msum) {
  int s = blockIdx.x;
  const float* m = mask + (size_t)s * NN;
  int t = threadIdx.x;
  float v = m[t] + m[t + 256] + m[t + 512] + m[t + 768];
  for (int o = 32; o; o >>= 1) v += __shfl_down(v, o);
  __shared__ float ps[4];
  if ((t & 63) == 0) ps[t >> 6] = v;
  __syncthreads();
  if (t == 0) msum[s] = ps[0] + ps[1] + ps[2] + ps[3];
}

// ---- squaring GEMM: C = A @ B (B given transposed). Writes newP bf16,
// psi = newP - oldP (f32 subtract), optionally C^T (offT>=0).
// 128x128 tile, BK=32, 4 waves, global_load_lds staging, XCD swizzle.
__global__ __launch_bounds__(256)
void k_square(char* ws, int offA, int offB, int offC, int offOld, int offPsi,
              int offT) {
  __shared__ u16 sh[8192];  // 16 KB: lA [128][32] | lB [128][32]
  u16* lA = sh;
  u16* lB = sh + 4096;

  unsigned nwg = gridDim.x, wg = blockIdx.x;
  unsigned newid = (wg & 7) * (nwg >> 3) + (wg >> 3);  // slice-per-XCD
  int z = newid >> 6;
  int by = (newid >> 3) & 7, bx = newid & 7;

  char* base = ws + SLICE0 + (size_t)z * PS_BYTES;
  const u16* A   = (const u16*)(base + offA);
  const u16* Bt  = (const u16*)(base + offB);
  u16* C         = (u16*)(base + offC);
  const u16* Old = (const u16*)(base + offOld);
  u16* Psi       = (u16*)(base + offPsi);

  const int tid = threadIdx.x;
  const int lane = tid & 63, wave = tid >> 6;
  const int wr = wave >> 1, wc = wave & 1;
  const int l16 = lane & 15, lk = lane >> 4;
  const int bm = by * 128, bn = bx * 128;

  const u16* gA = A + (size_t)(bm + (tid >> 2)) * NN + ((tid & 3) << 3);
  const u16* gB = Bt + (size_t)(bn + (tid >> 2)) * NN + ((tid & 3) << 3);
  u16* lA0 = lA + wave * 512;
  u16* lA1 = lA + 2048 + wave * 512;
  u16* lB0 = lB + wave * 512;
  u16* lB1 = lB + 2048 + wave * 512;

  f32x4 acc[4][4] = {};
  for (int k0 = 0; k0 < NN; k0 += 32) {
    GL16(gA + k0, lA0);
    GL16(gA + 64 * NN + k0, lA1);
    GL16(gB + k0, lB0);
    GL16(gB + 64 * NN + k0, lB1);
    __syncthreads();  // vmcnt(0) drain -> LDS tile ready
    bfx8 af[4], bf[4];
#pragma unroll
    for (int m = 0; m < 4; ++m)
      af[m] = *(const bfx8*)&lA[(wr * 64 + m * 16 + l16) * 32 + lk * 8];
#pragma unroll
    for (int n = 0; n < 4; ++n)
      bf[n] = *(const bfx8*)&lB[(wc * 64 + n * 16 + l16) * 32 + lk * 8];
#pragma unroll
    for (int m = 0; m < 4; ++m)
#pragma unroll
      for (int n = 0; n < 4; ++n)
        acc[m][n] = __builtin_amdgcn_mfma_f32_16x16x32_bf16(af[m], bf[n], acc[m][n], 0, 0, 0);
    __syncthreads();  // all reads done before next overwrite
  }

  // C + psi (f32 subtract from accumulator, bf16 store)
#pragma unroll
  for (int m = 0; m < 4; ++m) {
    int row0 = bm + wr * 64 + m * 16 + lk * 4;
#pragma unroll
    for (int n = 0; n < 4; ++n) {
      int col = bn + wc * 64 + n * 16 + l16;
#pragma unroll
      for (int r = 0; r < 4; ++r) {
        size_t idx = (size_t)(row0 + r) * NN + col;
        float v = acc[m][n][r];
        C[idx] = f2b(v);
        Psi[idx] = f2b(v - b2f(Old[idx]));
      }
    }
  }

  // C^T via per-wave LDS bounce: 4 passes of 16 out-rows, 16B stores
  if (offT >= 0) {
    u16* T = (u16*)(base + offT);
    u16* reg = sh + wave * 1152;  // [16][72] u16, 16B-aligned rows
#pragma unroll
    for (int n = 0; n < 4; ++n) {
      __syncthreads();
#pragma unroll
      for (int m = 0; m < 4; ++m) {
        u16x4 pk = {f2b(acc[m][n][0]), f2b(acc[m][n][1]),
                    f2b(acc[m][n][2]), f2b(acc[m][n][3])};
        *(u16x4*)&reg[l16 * 72 + m * 16 + lk * 4] = pk;
      }
      __syncthreads();
#pragma unroll
      for (int h = 0; h < 2; ++h) {
        int row = (lane >> 3) + 8 * h;
        int c8 = lane & 7;
        uint4 v = *(const uint4*)&reg[row * 72 + c8 * 8];
        *(uint4*)&T[(size_t)(bn + wc * 64 + n * 16 + row) * NN + bm + wr * 64 + c8 * 8] = v;
      }
    }
  }
}

// ---- feature GEMM: [1024x64] = A[1024x1024] @ B (Bt [64][1024]).
// V=0: A=psi_sub, B=XT  -> scT_sub + pool(1+sub)
// V=1: A=P8,      B=XT  -> U (f32) + UT
// V=2: A=P8,      B=UT  -> pool F0 (k=0); sc3=|acc-U| -> scT3 + pool(4)
// V=3: A=psi_j,   B=scT_i -> pool(5+pair)
template <int V>
__global__ __launch_bounds__(256)
void k_feat(char* ws, int sliceBase, float* __restrict__ pooled) {
  __shared__ u16 lA[128 * 32];
  __shared__ u16 lB[64 * 32];
  unsigned nwg = gridDim.x, wg = blockIdx.x;
  unsigned newid = (wg & 7) * (nwg >> 3) + (wg >> 3);  // 8-block groups per XCD
  int by = newid & 7;
  int zz = newid >> 3;
  int s, sub;
  if (V == 0)      { s = zz / 3; sub = zz % 3; }
  else if (V == 3) { s = zz / 6; sub = zz % 6; }
  else             { s = zz;     sub = 0;     }
  char* base = ws + SLICE0 + (size_t)s * PS_BYTES;

  const u16* A;
  const u16* Bt;
  int kidx = 0;
  if (V == 0) {
    A = (const u16*)(base + OFF_PSI0 + (size_t)sub * MB2);
    Bt = (const u16*)(base + OFF_XT);
    kidx = 1 + sub;
  } else if (V == 1) {
    A = (const u16*)(base + OFF_R0);
    Bt = (const u16*)(base + OFF_XT);
  } else if (V == 2) {
    A = (const u16*)(base + OFF_R0);
    Bt = (const u16*)(base + OFF_UT);
  } else {
    int ii = (sub >= 3) ? 3 : (sub >= 1 ? 2 : 1);
    int jj = sub - (ii * (ii - 1)) / 2;
    A = (const u16*)(base + OFF_PSI0 + (size_t)jj * MB2);
    Bt = (const u16*)(base + OFF_SCT + (size_t)ii * 131072u);
    kidx = 5 + sub;
  }
  float* U = (float*)(base + OFF_U);
  u16* UT = (u16*)(base + OFF_UT);
  u16* scT = (u16*)(base + OFF_SCT + (size_t)(V == 0 ? sub : 3) * 131072u);
  int poolBase = (sliceBase + s) * (KFEAT * FF);

  const int tid = threadIdx.x;
  const int lane = tid & 63, wave = tid >> 6;
  const int wr = wave >> 1, wc = wave & 1;
  const int l16 = lane & 15, lk = lane >> 4;
  const int bm = by * 128;

  const u16* gA = A + (size_t)(bm + (tid >> 2)) * NN + ((tid & 3) << 3);
  const u16* gB = Bt + (size_t)(tid >> 2) * NN + ((tid & 3) << 3);
  u16* lA0 = lA + wave * 512;
  u16* lA1 = lA + 2048 + wave * 512;
  u16* lB0 = lB + wave * 512;

  f32x4 acc[4][2] = {};
  for (int k0 = 0; k0 < NN; k0 += 32) {
    GL16(gA + k0, lA0);
    GL16(gA + 64 * NN + k0, lA1);
    GL16(gB + k0, lB0);
    __syncthreads();
    bfx8 af[4], bfr[2];
#pragma unroll
    for (int m = 0; m < 4; ++m)
      af[m] = *(const bfx8*)&lA[(wr * 64 + m * 16 + l16) * 32 + lk * 8];
#pragma unroll
    for (int n = 0; n < 2; ++n)
      bfr[n] = *(const bfx8*)&lB[(wc * 32 + n * 16 + l16) * 32 + lk * 8];
#pragma unroll
    for (int m = 0; m < 4; ++m)
#pragma unroll
      for (int n = 0; n < 2; ++n)
        acc[m][n] = __builtin_amdgcn_mfma_f32_16x16x32_bf16(af[m], bfr[n], acc[m][n], 0, 0, 0);
    __syncthreads();
  }

  float ps[2] = {0.f, 0.f};
  float psF0[2] = {0.f, 0.f};

#pragma unroll
  for (int m = 0; m < 4; ++m) {
    int row0 = bm + wr * 64 + m * 16 + lk * 4;
#pragma unroll
    for (int n = 0; n < 2; ++n) {
      int col = wc * 32 + n * 16 + l16;
      float v0 = acc[m][n][0], v1 = acc[m][n][1], v2 = acc[m][n][2], v3 = acc[m][n][3];
      if (V == 0 || V == 3) {
        v0 = fabsf(v0); v1 = fabsf(v1); v2 = fabsf(v2); v3 = fabsf(v3);
        ps[n] += v0 + v1 + v2 + v3;
        if (V == 0) {
          u16x4 pk = {f2b(v0), f2b(v1), f2b(v2), f2b(v3)};
          *(u16x4*)&scT[(size_t)col * NN + row0] = pk;
        }
      } else if (V == 1) {
        U[(size_t)(row0 + 0) * FF + col] = v0;
        U[(size_t)(row0 + 1) * FF + col] = v1;
        U[(size_t)(row0 + 2) * FF + col] = v2;
        U[(size_t)(row0 + 3) * FF + col] = v3;
        u16x4 pk = {f2b(v0), f2b(v1), f2b(v2), f2b(v3)};
        *(u16x4*)&UT[(size_t)col * NN + row0] = pk;
      } else {  // V == 2
        psF0[n] += v0 + v1 + v2 + v3;
        float u0 = U[(size_t)(row0 + 0) * FF + col];
        float u1 = U[(size_t)(row0 + 1) * FF + col];
        float u2 = U[(size_t)(row0 + 2) * FF + col];
        float u3 = U[(size_t)(row0 + 3) * FF + col];
        float d0 = fabsf(v0 - u0), d1 = fabsf(v1 - u1);
        float d2 = fabsf(v2 - u2), d3 = fabsf(v3 - u3);
        ps[n] += d0 + d1 + d2 + d3;
        u16x4 pk = {f2b(d0), f2b(d1), f2b(d2), f2b(d3)};
        *(u16x4*)&scT[(size_t)col * NN + row0] = pk;
      }
    }
  }

  if (V != 1) {
#pragma unroll
    for (int n = 0; n < 2; ++n) {
      float v = ps[n];
      v += __shfl_xor(v, 16);
      v += __shfl_xor(v, 32);
      if (lane < 16) {
        int kk = (V == 2) ? 4 : kidx;
        atomicAdd(&pooled[poolBase + kk * FF + wc * 32 + n * 16 + lane], v);
      }
      if (V == 2) {
        float f = psF0[n];
        f += __shfl_xor(f, 16);
        f += __shfl_xor(f, 32);
        if (lane < 16)
          atomicAdd(&pooled[poolBase + 0 * FF + wc * 32 + n * 16 + lane], f);
      }
    }
  }
}

__global__ void k_final(const float* __restrict__ pooled, const float* __restrict__ msum,
                        float* __restrict__ out, int total) {
  int i = blockIdx.x * 256 + threadIdx.x;
  if (i < total) out[i] = pooled[i] / msum[i / (KFEAT * FF)];
}

extern "C" void kernel_launch(void* const* d_in, const int* in_sizes, int n_in,
                              void* d_out, int out_size, void* d_ws, size_t ws_size,
                              hipStream_t stream) {
  const float* P = (const float*)d_in[0];
  const float* X = (const float*)d_in[1];
  const float* mask = (const float*)d_in[2];
  float* out = (float*)d_out;
  char* ws = (char*)d_ws;
  float* pooled = (float*)ws;
  float* msum = (float*)(ws + MSUM_OFF);

  hipMemsetAsync(pooled, 0, POOL_BYTES, stream);
  k_msum<<<NSLICE, 256, 0, stream>>>(mask, msum);

  int S = 1;
  if (ws_size > SLICE0 + PS_BYTES) S = (int)((ws_size - SLICE0) / PS_BYTES);
  if (S > NSLICE) S = NSLICE;
  if (S < 1) S = 1;

  for (int b0 = 0; b0 < NSLICE; b0 += S) {
    int n = (NSLICE - b0 < S) ? (NSLICE - b0) : S;
    k_convP<<<dim3(16, 16, n), 256, 0, stream>>>(P, ws, b0);
    k_convX<<<dim3(16, 1, n), 256, 0, stream>>>(X, ws, b0);
    // P2 = P@P -> R1, psi0 -> PSI0, P2^T -> PSI2 (scratch until sq2)
    k_square<<<64 * n, 256, 0, stream>>>(ws, OFF_R0, OFF_T, OFF_R1, OFF_R0, OFF_PSI0, (int)OFF_PSI2);
    // P4 = P2@P2 -> R2, psi1 -> PSI1, P4^T -> T
    k_square<<<64 * n, 256, 0, stream>>>(ws, OFF_R1, OFF_PSI2, OFF_R2, OFF_R1, OFF_PSI1, (int)OFF_T);
    // P8 = P4@P4 -> R0, psi2 -> PSI2 (overwrites dead P2^T)
    k_square<<<64 * n, 256, 0, stream>>>(ws, OFF_R2, OFF_T, OFF_R0, OFF_R2, OFF_PSI2, -1);
    // sc_i = |psi_i X| ; U = P8 X ; P8 U (F0 + sc3) ; F2 pairs
    k_feat<0><<<24 * n, 256, 0, stream>>>(ws, b0, pooled);
    k_feat<1><<<8 * n, 256, 0, stream>>>(ws, b0, pooled);
    k_feat<2><<<8 * n, 256, 0, stream>>>(ws, b0, pooled);
    k_feat<3><<<48 * n, 256, 0, stream>>>(ws, b0, pooled);
  }
  int total = NSLICE * KFEAT * FF;
  k_final<<<(total + 255) / 256, 256, 0, stream>>>(pooled, msum, out, total);
}

// Round 3
// 669.924 us; speedup vs baseline: 1.1280x; 1.0092x over previous
//
#include <hip/hip_runtime.h>

typedef unsigned short u16;
typedef __bf16 bfx8 __attribute__((ext_vector_type(8)));
typedef float f32x4 __attribute__((ext_vector_type(4)));
typedef unsigned short u16x4 __attribute__((ext_vector_type(4)));

#define NN 1024
#define FF 64
#define NSLICE 32
#define KFEAT 11

// ---- workspace layout ----
#define POOL_BYTES (NSLICE * KFEAT * FF * 4)  // 90112
#define MSUM_OFF   POOL_BYTES
#define SLICE0     ((size_t)1 << 20)
#define MB2        (2u * 1024u * 1024u)
#define OFF_R0     0u
#define OFF_R1     (1u * MB2)
#define OFF_R2     (2u * MB2)
#define OFF_T      (3u * MB2)
#define OFF_PSI0   (4u * MB2)
#define OFF_PSI1   (5u * MB2)
#define OFF_PSI2   (6u * MB2)
#define OFF_XT     (7u * MB2)                    // 128KB  bf16 [64][1024]
#define OFF_SCT    (7u * MB2 + 131072u)          // 4x128KB bf16 [64][1024]
#define OFF_U      (7u * MB2 + 131072u * 5u)     // 256KB  f32 [1024][64]
#define OFF_UT     (7u * MB2 + 131072u * 7u)     // 128KB  bf16 [64][1024]
#define PS_BYTES   ((size_t)(7u * MB2 + 131072u * 8u))  // 15728640

// async global->LDS, 16B per lane; LDS dest = wave-uniform base + lane*16
#define GL16(g, l) __builtin_amdgcn_global_load_lds( \
    (const __attribute__((address_space(1))) unsigned int*)(g), \
    (__attribute__((address_space(3))) unsigned int*)(l), 16, 0, 0)

// Bank-conflict-free chunk rotation (rule #21: linear LDS dest, permuted
// global source + matching permuted read):
//   physical 16B slot of logical (row, lk) = row*4 + ((lk + (row>>1)) & 3)
// Staging lane (srow=tid>>2, c=tid&3) therefore fetches global chunk
//   (c - (srow>>1)) & 3  ==  (c - (tid>>3)) & 3
// Read of logical (row, lk) uses rotation ((lk + (l16>>1)) & 3) since
// (row>>1)&3 == (l16>>1)&3 for all fragment rows (row = 16*m' + l16 + 64*w).
// Each consecutive-8-lane phase of ds_read_b128 then hits all 8 bank-quads
// exactly once (was 2 quads -> 4-way conflict).

__device__ __forceinline__ u16 f2b(float v) {
  __bf16 h = (__bf16)v;
  return __builtin_bit_cast(u16, h);
}
__device__ __forceinline__ float b2f(u16 u) {
  return (float)__builtin_bit_cast(__bf16, u);
}

// ---- P slice: f32 -> bf16 row-major (R0) + bf16 transposed (T) ----
__global__ void k_convP(const float* __restrict__ P, char* ws, int sliceBase) {
  __shared__ float tile[64][65];
  int s = blockIdx.z;
  const float* Ps = P + (size_t)(sliceBase + s) * NN * NN;
  char* base = ws + SLICE0 + (size_t)s * PS_BYTES;
  u16* Pb  = (u16*)(base + OFF_R0);
  u16* PbT = (u16*)(base + OFF_T);
  int r0 = blockIdx.y * 64, c0 = blockIdx.x * 64;
  int tid = threadIdx.x;
  int tc = tid & 15, tr = tid >> 4;  // 16 rows per iter, float4 per lane
  for (int rr = 0; rr < 64; rr += 16) {
    int r = rr + tr;
    float4 v = *(const float4*)&Ps[(size_t)(r0 + r) * NN + c0 + tc * 4];
    tile[r][tc * 4 + 0] = v.x;
    tile[r][tc * 4 + 1] = v.y;
    tile[r][tc * 4 + 2] = v.z;
    tile[r][tc * 4 + 3] = v.w;
    u16x4 pk = {f2b(v.x), f2b(v.y), f2b(v.z), f2b(v.w)};
    *(u16x4*)&Pb[(size_t)(r0 + r) * NN + c0 + tc * 4] = pk;
  }
  __syncthreads();
  for (int it = 0; it < 4; ++it) {
    int oc = (tid >> 4) + it * 16;  // src col = out row
    int ch = tid & 15;              // 4-src-row chunk
    u16x4 pk = {f2b(tile[ch * 4 + 0][oc]), f2b(tile[ch * 4 + 1][oc]),
                f2b(tile[ch * 4 + 2][oc]), f2b(tile[ch * 4 + 3][oc])};
    *(u16x4*)&PbT[(size_t)(c0 + oc) * NN + r0 + ch * 4] = pk;
  }
}

// ---- X slice: f32 [1024][64] -> bf16 XT [64][1024] ----
__global__ void k_convX(const float* __restrict__ X, char* ws, int sliceBase) {
  __shared__ float tile[64][65];
  int s = blockIdx.z;
  const float* Xs = X + (size_t)(sliceBase + s) * NN * FF;
  u16* XT = (u16*)(ws + SLICE0 + (size_t)s * PS_BYTES + OFF_XT);
  int r0 = blockIdx.x * 64;
  int tx = threadIdx.x & 63, ty = threadIdx.x >> 6;
  for (int rr = 0; rr < 64; rr += 4)
    tile[rr + ty][tx] = Xs[(size_t)(r0 + rr + ty) * FF + tx];
  __syncthreads();
  for (int rr = 0; rr < 64; rr += 4)
    XT[(size_t)(rr + ty) * NN + r0 + tx] = f2b(tile[tx][rr + ty]);
}

__global__ void k_msum(const float* __restrict__ mask, float* msum) {
  int s = blockIdx.x;
  const float* m = mask + (size_t)s * NN;
  int t = threadIdx.x;
  float v = m[t] + m[t + 256] + m[t + 512] + m[t + 768];
  for (int o = 32; o; o >>= 1) v += __shfl_down(v, o);
  __shared__ float ps[4];
  if ((t & 63) == 0) ps[t >> 6] = v;
  __syncthreads();
  if (t == 0) msum[s] = ps[0] + ps[1] + ps[2] + ps[3];
}

// ---- squaring GEMM: C = A @ B (B given transposed). Writes newP bf16,
// psi = newP - oldP (f32 subtract), optionally C^T (offT>=0).
// 128x128 tile, BK=32, 4 waves, global_load_lds staging, XCD swizzle,
// conflict-free chunk-rotated LDS layout.
__global__ __launch_bounds__(256)
void k_square(char* ws, int offA, int offB, int offC, int offOld, int offPsi,
              int offT) {
  __shared__ u16 sh[8192];  // 16 KB: lA [128][32] | lB [128][32]
  u16* lA = sh;
  u16* lB = sh + 4096;

  unsigned nwg = gridDim.x, wg = blockIdx.x;
  unsigned newid = (wg & 7) * (nwg >> 3) + (wg >> 3);  // slice-per-XCD
  int z = newid >> 6;
  int by = (newid >> 3) & 7, bx = newid & 7;

  char* base = ws + SLICE0 + (size_t)z * PS_BYTES;
  const u16* A   = (const u16*)(base + offA);
  const u16* Bt  = (const u16*)(base + offB);
  u16* C         = (u16*)(base + offC);
  const u16* Old = (const u16*)(base + offOld);
  u16* Psi       = (u16*)(base + offPsi);

  const int tid = threadIdx.x;
  const int lane = tid & 63, wave = tid >> 6;
  const int wr = wave >> 1, wc = wave & 1;
  const int l16 = lane & 15, lk = lane >> 4;
  const int bm = by * 128, bn = bx * 128;

  // inverse-permuted global chunk for linear LDS dest
  const int pc = (((tid & 3) - (tid >> 3)) & 3) << 3;
  const u16* gA = A + (size_t)(bm + (tid >> 2)) * NN + pc;
  const u16* gB = Bt + (size_t)(bn + (tid >> 2)) * NN + pc;
  u16* lA0 = lA + wave * 512;
  u16* lA1 = lA + 2048 + wave * 512;
  u16* lB0 = lB + wave * 512;
  u16* lB1 = lB + 2048 + wave * 512;

  const int rot = ((lk + (l16 >> 1)) & 3) << 3;  // permuted read chunk

  f32x4 acc[4][4] = {};
  for (int k0 = 0; k0 < NN; k0 += 32) {
    GL16(gA + k0, lA0);
    GL16(gA + 64 * NN + k0, lA1);
    GL16(gB + k0, lB0);
    GL16(gB + 64 * NN + k0, lB1);
    __syncthreads();  // vmcnt(0) drain -> LDS tile ready
    bfx8 af[4], bf[4];
#pragma unroll
    for (int m = 0; m < 4; ++m)
      af[m] = *(const bfx8*)&lA[(wr * 64 + m * 16 + l16) * 32 + rot];
#pragma unroll
    for (int n = 0; n < 4; ++n)
      bf[n] = *(const bfx8*)&lB[(wc * 64 + n * 16 + l16) * 32 + rot];
#pragma unroll
    for (int m = 0; m < 4; ++m)
#pragma unroll
      for (int n = 0; n < 4; ++n)
        acc[m][n] = __builtin_amdgcn_mfma_f32_16x16x32_bf16(af[m], bf[n], acc[m][n], 0, 0, 0);
    __syncthreads();  // all reads done before next overwrite
  }

  // C + psi (f32 subtract from accumulator, bf16 store)
#pragma unroll
  for (int m = 0; m < 4; ++m) {
    int row0 = bm + wr * 64 + m * 16 + lk * 4;
#pragma unroll
    for (int n = 0; n < 4; ++n) {
      int col = bn + wc * 64 + n * 16 + l16;
#pragma unroll
      for (int r = 0; r < 4; ++r) {
        size_t idx = (size_t)(row0 + r) * NN + col;
        float v = acc[m][n][r];
        C[idx] = f2b(v);
        Psi[idx] = f2b(v - b2f(Old[idx]));
      }
    }
  }

  // C^T via per-wave LDS bounce: 4 passes of 16 out-rows, 16B stores
  if (offT >= 0) {
    u16* T = (u16*)(base + offT);
    u16* reg = sh + wave * 1152;  // [16][72] u16, 16B-aligned rows
#pragma unroll
    for (int n = 0; n < 4; ++n) {
      __syncthreads();
#pragma unroll
      for (int m = 0; m < 4; ++m) {
        u16x4 pk = {f2b(acc[m][n][0]), f2b(acc[m][n][1]),
                    f2b(acc[m][n][2]), f2b(acc[m][n][3])};
        *(u16x4*)&reg[l16 * 72 + m * 16 + lk * 4] = pk;
      }
      __syncthreads();
#pragma unroll
      for (int h = 0; h < 2; ++h) {
        int row = (lane >> 3) + 8 * h;
        int c8 = lane & 7;
        uint4 v = *(const uint4*)&reg[row * 72 + c8 * 8];
        *(uint4*)&T[(size_t)(bn + wc * 64 + n * 16 + row) * NN + bm + wr * 64 + c8 * 8] = v;
      }
    }
  }
}

// ---- feature GEMM: [1024x64] = A[1024x1024] @ B (Bt [64][1024]).
// V=0: A=psi_sub, B=XT  -> scT_sub + pool(1+sub)
// V=1: A=P8,      B=XT  -> U (f32) + UT
// V=2: A=P8,      B=UT  -> pool F0 (k=0); sc3=|acc-U| -> scT3 + pool(4)
// V=3: A=psi_j,   B=scT_i -> pool(5+pair)
template <int V>
__global__ __launch_bounds__(256)
void k_feat(char* ws, int sliceBase, float* __restrict__ pooled) {
  __shared__ u16 lA[128 * 32];
  __shared__ u16 lB[64 * 32];
  unsigned nwg = gridDim.x, wg = blockIdx.x;
  unsigned newid = (wg & 7) * (nwg >> 3) + (wg >> 3);  // 8-block groups per XCD
  int by = newid & 7;
  int zz = newid >> 3;
  int s, sub;
  if (V == 0)      { s = zz / 3; sub = zz % 3; }
  else if (V == 3) { s = zz / 6; sub = zz % 6; }
  else             { s = zz;     sub = 0;     }
  char* base = ws + SLICE0 + (size_t)s * PS_BYTES;

  const u16* A;
  const u16* Bt;
  int kidx = 0;
  if (V == 0) {
    A = (const u16*)(base + OFF_PSI0 + (size_t)sub * MB2);
    Bt = (const u16*)(base + OFF_XT);
    kidx = 1 + sub;
  } else if (V == 1) {
    A = (const u16*)(base + OFF_R0);
    Bt = (const u16*)(base + OFF_XT);
  } else if (V == 2) {
    A = (const u16*)(base + OFF_R0);
    Bt = (const u16*)(base + OFF_UT);
  } else {
    int ii = (sub >= 3) ? 3 : (sub >= 1 ? 2 : 1);
    int jj = sub - (ii * (ii - 1)) / 2;
    A = (const u16*)(base + OFF_PSI0 + (size_t)jj * MB2);
    Bt = (const u16*)(base + OFF_SCT + (size_t)ii * 131072u);
    kidx = 5 + sub;
  }
  float* U = (float*)(base + OFF_U);
  u16* UT = (u16*)(base + OFF_UT);
  u16* scT = (u16*)(base + OFF_SCT + (size_t)(V == 0 ? sub : 3) * 131072u);
  int poolBase = (sliceBase + s) * (KFEAT * FF);

  const int tid = threadIdx.x;
  const int lane = tid & 63, wave = tid >> 6;
  const int wr = wave >> 1, wc = wave & 1;
  const int l16 = lane & 15, lk = lane >> 4;
  const int bm = by * 128;

  const int pc = (((tid & 3) - (tid >> 3)) & 3) << 3;
  const u16* gA = A + (size_t)(bm + (tid >> 2)) * NN + pc;
  const u16* gB = Bt + (size_t)(tid >> 2) * NN + pc;
  u16* lA0 = lA + wave * 512;
  u16* lA1 = lA + 2048 + wave * 512;
  u16* lB0 = lB + wave * 512;

  const int rot = ((lk + (l16 >> 1)) & 3) << 3;

  f32x4 acc[4][2] = {};
  for (int k0 = 0; k0 < NN; k0 += 32) {
    GL16(gA + k0, lA0);
    GL16(gA + 64 * NN + k0, lA1);
    GL16(gB + k0, lB0);
    __syncthreads();
    bfx8 af[4], bfr[2];
#pragma unroll
    for (int m = 0; m < 4; ++m)
      af[m] = *(const bfx8*)&lA[(wr * 64 + m * 16 + l16) * 32 + rot];
#pragma unroll
    for (int n = 0; n < 2; ++n)
      bfr[n] = *(const bfx8*)&lB[(wc * 32 + n * 16 + l16) * 32 + rot];
#pragma unroll
    for (int m = 0; m < 4; ++m)
#pragma unroll
      for (int n = 0; n < 2; ++n)
        acc[m][n] = __builtin_amdgcn_mfma_f32_16x16x32_bf16(af[m], bfr[n], acc[m][n], 0, 0, 0);
    __syncthreads();
  }

  float ps[2] = {0.f, 0.f};
  float psF0[2] = {0.f, 0.f};

#pragma unroll
  for (int m = 0; m < 4; ++m) {
    int row0 = bm + wr * 64 + m * 16 + lk * 4;
#pragma unroll
    for (int n = 0; n < 2; ++n) {
      int col = wc * 32 + n * 16 + l16;
      float v0 = acc[m][n][0], v1 = acc[m][n][1], v2 = acc[m][n][2], v3 = acc[m][n][3];
      if (V == 0 || V == 3) {
        v0 = fabsf(v0); v1 = fabsf(v1); v2 = fabsf(v2); v3 = fabsf(v3);
        ps[n] += v0 + v1 + v2 + v3;
        if (V == 0) {
          u16x4 pk = {f2b(v0), f2b(v1), f2b(v2), f2b(v3)};
          *(u16x4*)&scT[(size_t)col * NN + row0] = pk;
        }
      } else if (V == 1) {
        U[(size_t)(row0 + 0) * FF + col] = v0;
        U[(size_t)(row0 + 1) * FF + col] = v1;
        U[(size_t)(row0 + 2) * FF + col] = v2;
        U[(size_t)(row0 + 3) * FF + col] = v3;
        u16x4 pk = {f2b(v0), f2b(v1), f2b(v2), f2b(v3)};
        *(u16x4*)&UT[(size_t)col * NN + row0] = pk;
      } else {  // V == 2
        psF0[n] += v0 + v1 + v2 + v3;
        float u0 = U[(size_t)(row0 + 0) * FF + col];
        float u1 = U[(size_t)(row0 + 1) * FF + col];
        float u2 = U[(size_t)(row0 + 2) * FF + col];
        float u3 = U[(size_t)(row0 + 3) * FF + col];
        float d0 = fabsf(v0 - u0), d1 = fabsf(v1 - u1);
        float d2 = fabsf(v2 - u2), d3 = fabsf(v3 - u3);
        ps[n] += d0 + d1 + d2 + d3;
        u16x4 pk = {f2b(d0), f2b(d1), f2b(d2), f2b(d3)};
        *(u16x4*)&scT[(size_t)col * NN + row0] = pk;
      }
    }
  }

  if (V != 1) {
#pragma unroll
    for (int n = 0; n < 2; ++n) {
      float v = ps[n];
      v += __shfl_xor(v, 16);
      v += __shfl_xor(v, 32);
      if (lane < 16) {
        int kk = (V == 2) ? 4 : kidx;
        atomicAdd(&pooled[poolBase + kk * FF + wc * 32 + n * 16 + lane], v);
      }
      if (V == 2) {
        float f = psF0[n];
        f += __shfl_xor(f, 16);
        f += __shfl_xor(f, 32);
        if (lane < 16)
          atomicAdd(&pooled[poolBase + 0 * FF + wc * 32 + n * 16 + lane], f);
      }
    }
  }
}

__global__ void k_final(const float* __restrict__ pooled, const float* __restrict__ msum,
                        float* __restrict__ out, int total) {
  int i = blockIdx.x * 256 + threadIdx.x;
  if (i < total) out[i] = pooled[i] / msum[i / (KFEAT * FF)];
}

extern "C" void kernel_launch(void* const* d_in, const int* in_sizes, int n_in,
                              void* d_out, int out_size, void* d_ws, size_t ws_size,
                              hipStream_t stream) {
  const float* P = (const float*)d_in[0];
  const float* X = (const float*)d_in[1];
  const float* mask = (const float*)d_in[2];
  float* out = (float*)d_out;
  char* ws = (char*)d_ws;
  float* pooled = (float*)ws;
  float* msum = (float*)(ws + MSUM_OFF);

  hipMemsetAsync(pooled, 0, POOL_BYTES, stream);
  k_msum<<<NSLICE, 256, 0, stream>>>(mask, msum);

  int S = 1;
  if (ws_size > SLICE0 + PS_BYTES) S = (int)((ws_size - SLICE0) / PS_BYTES);
  if (S > NSLICE) S = NSLICE;
  if (S < 1) S = 1;

  for (int b0 = 0; b0 < NSLICE; b0 += S) {
    int n = (NSLICE - b0 < S) ? (NSLICE - b0) : S;
    k_convP<<<dim3(16, 16, n), 256, 0, stream>>>(P, ws, b0);
    k_convX<<<dim3(16, 1, n), 256, 0, stream>>>(X, ws, b0);
    // P2 = P@P -> R1, psi0 -> PSI0, P2^T -> PSI2 (scratch until sq2)
    k_square<<<64 * n, 256, 0, stream>>>(ws, OFF_R0, OFF_T, OFF_R1, OFF_R0, OFF_PSI0, (int)OFF_PSI2);
    // P4 = P2@P2 -> R2, psi1 -> PSI1, P4^T -> T
    k_square<<<64 * n, 256, 0, stream>>>(ws, OFF_R1, OFF_PSI2, OFF_R2, OFF_R1, OFF_PSI1, (int)OFF_T);
    // P8 = P4@P4 -> R0, psi2 -> PSI2 (overwrites dead P2^T)
    k_square<<<64 * n, 256, 0, stream>>>(ws, OFF_R2, OFF_T, OFF_R0, OFF_R2, OFF_PSI2, -1);
    // sc_i = |psi_i X| ; U = P8 X ; P8 U (F0 + sc3) ; F2 pairs
    k_feat<0><<<24 * n, 256, 0, stream>>>(ws, b0, pooled);
    k_feat<1><<<8 * n, 256, 0, stream>>>(ws, b0, pooled);
    k_feat<2><<<8 * n, 256, 0, stream>>>(ws, b0, pooled);
    k_feat<3><<<48 * n, 256, 0, stream>>>(ws, b0, pooled);
  }
  int total = NSLICE * KFEAT * FF;
  k_final<<<(total + 255) / 256, 256, 0, stream>>>(pooled, msum, out, total);
}

// Round 4
// 645.891 us; speedup vs baseline: 1.1699x; 1.0372x over previous
//
#include <hip/hip_runtime.h>

typedef unsigned short u16;
typedef __bf16 bfx8 __attribute__((ext_vector_type(8)));
typedef float f32x4 __attribute__((ext_vector_type(4)));
typedef unsigned short u16x4 __attribute__((ext_vector_type(4)));

#define NN 1024
#define FF 64
#define NSLICE 32
#define KFEAT 11

// ---- workspace layout ----
#define POOL_BYTES (NSLICE * KFEAT * FF * 4)  // 90112
#define MSUM_OFF   POOL_BYTES
#define SLICE0     ((size_t)1 << 20)
#define MB2        (2u * 1024u * 1024u)
#define OFF_R0     0u
#define OFF_R1     (1u * MB2)
#define OFF_R2     (2u * MB2)
#define OFF_T      (3u * MB2)
#define OFF_PSI0   (4u * MB2)
#define OFF_PSI1   (5u * MB2)
#define OFF_PSI2   (6u * MB2)
#define OFF_XT     (7u * MB2)                    // 128KB  bf16 [64][1024]
#define OFF_SCT    (7u * MB2 + 131072u)          // 4x128KB bf16 [64][1024]
#define OFF_U      (7u * MB2 + 131072u * 5u)     // 256KB  f32 [1024][64]
#define OFF_UT     (7u * MB2 + 131072u * 7u)     // 128KB  bf16 [64][1024]
#define PS_BYTES   ((size_t)(7u * MB2 + 131072u * 8u))  // 15728640

// async global->LDS, 16B per lane; LDS dest = wave-uniform base + lane*16
#define GL16(g, l) __builtin_amdgcn_global_load_lds( \
    (const __attribute__((address_space(1))) unsigned int*)(g), \
    (__attribute__((address_space(3))) unsigned int*)(l), 16, 0, 0)

// Bank-conflict-free chunk rotation (rule #21): linear LDS dest, permuted
// global source chunk (c - (tid>>3))&3, matching permuted read rotation
// ((lk + (l16>>1))&3). Verified conflict counter 9.17M -> 0.79M.

__device__ __forceinline__ u16 f2b(float v) {
  __bf16 h = (__bf16)v;
  return __builtin_bit_cast(u16, h);
}
__device__ __forceinline__ float b2f(u16 u) {
  return (float)__builtin_bit_cast(__bf16, u);
}

// ---- P slice: f32 -> bf16 row-major (R0) + bf16 transposed (T) ----
__global__ void k_convP(const float* __restrict__ P, char* ws, int sliceBase) {
  __shared__ float tile[64][65];
  int s = blockIdx.z;
  const float* Ps = P + (size_t)(sliceBase + s) * NN * NN;
  char* base = ws + SLICE0 + (size_t)s * PS_BYTES;
  u16* Pb  = (u16*)(base + OFF_R0);
  u16* PbT = (u16*)(base + OFF_T);
  int r0 = blockIdx.y * 64, c0 = blockIdx.x * 64;
  int tid = threadIdx.x;
  int tc = tid & 15, tr = tid >> 4;
  for (int rr = 0; rr < 64; rr += 16) {
    int r = rr + tr;
    float4 v = *(const float4*)&Ps[(size_t)(r0 + r) * NN + c0 + tc * 4];
    tile[r][tc * 4 + 0] = v.x;
    tile[r][tc * 4 + 1] = v.y;
    tile[r][tc * 4 + 2] = v.z;
    tile[r][tc * 4 + 3] = v.w;
    u16x4 pk = {f2b(v.x), f2b(v.y), f2b(v.z), f2b(v.w)};
    *(u16x4*)&Pb[(size_t)(r0 + r) * NN + c0 + tc * 4] = pk;
  }
  __syncthreads();
  for (int it = 0; it < 4; ++it) {
    int oc = (tid >> 4) + it * 16;
    int ch = tid & 15;
    u16x4 pk = {f2b(tile[ch * 4 + 0][oc]), f2b(tile[ch * 4 + 1][oc]),
                f2b(tile[ch * 4 + 2][oc]), f2b(tile[ch * 4 + 3][oc])};
    *(u16x4*)&PbT[(size_t)(c0 + oc) * NN + r0 + ch * 4] = pk;
  }
}

// ---- X slice: f32 [1024][64] -> bf16 XT [64][1024] ----
__global__ void k_convX(const float* __restrict__ X, char* ws, int sliceBase) {
  __shared__ float tile[64][65];
  int s = blockIdx.z;
  const float* Xs = X + (size_t)(sliceBase + s) * NN * FF;
  u16* XT = (u16*)(ws + SLICE0 + (size_t)s * PS_BYTES + OFF_XT);
  int r0 = blockIdx.x * 64;
  int tx = threadIdx.x & 63, ty = threadIdx.x >> 6;
  for (int rr = 0; rr < 64; rr += 4)
    tile[rr + ty][tx] = Xs[(size_t)(r0 + rr + ty) * FF + tx];
  __syncthreads();
  for (int rr = 0; rr < 64; rr += 4)
    XT[(size_t)(rr + ty) * NN + r0 + tx] = f2b(tile[tx][rr + ty]);
}

__global__ void k_msum(const float* __restrict__ mask, float* msum) {
  int s = blockIdx.x;
  const float* m = mask + (size_t)s * NN;
  int t = threadIdx.x;
  float v = m[t] + m[t + 256] + m[t + 512] + m[t + 768];
  for (int o = 32; o; o >>= 1) v += __shfl_down(v, o);
  __shared__ float ps[4];
  if ((t & 63) == 0) ps[t >> 6] = v;
  __syncthreads();
  if (t == 0) msum[s] = ps[0] + ps[1] + ps[2] + ps[3];
}

// ---- squaring GEMM: C = A @ B (B given transposed). Writes newP bf16,
// psi = newP - oldP (f32 subtract), optionally C^T (offT>=0).
// 128x128 tile, BK=32, 4 waves, global_load_lds, XCD swizzle, chunk-rotation
// LDS, double-buffered minimum-2-phase schedule (T3: stage t+1 before
// compute t, one barrier per K-step).
__global__ __launch_bounds__(256)
void k_square(char* ws, int offA, int offB, int offC, int offOld, int offPsi,
              int offT) {
  __shared__ u16 sh[16384];  // 32KB: lA[2][4096] @0 | lB[2][4096] @8192

  unsigned nwg = gridDim.x, wg = blockIdx.x;
  unsigned newid = (wg & 7) * (nwg >> 3) + (wg >> 3);  // slice-per-XCD
  int z = newid >> 6;
  int by = (newid >> 3) & 7, bx = newid & 7;

  char* base = ws + SLICE0 + (size_t)z * PS_BYTES;
  const u16* A   = (const u16*)(base + offA);
  const u16* Bt  = (const u16*)(base + offB);
  u16* C         = (u16*)(base + offC);
  const u16* Old = (const u16*)(base + offOld);
  u16* Psi       = (u16*)(base + offPsi);

  const int tid = threadIdx.x;
  const int lane = tid & 63, wave = tid >> 6;
  const int wr = wave >> 1, wc = wave & 1;
  const int l16 = lane & 15, lk = lane >> 4;
  const int bm = by * 128, bn = bx * 128;

  const int pc = (((tid & 3) - (tid >> 3)) & 3) << 3;
  const u16* gA = A + (size_t)(bm + (tid >> 2)) * NN + pc;
  const u16* gB = Bt + (size_t)(bn + (tid >> 2)) * NN + pc;
  const int rot = ((lk + (l16 >> 1)) & 3) << 3;

  f32x4 acc[4][4] = {};

#define SQ_STAGE(k0, buf)                                   \
  {                                                         \
    u16* dA = sh + (buf)*4096 + wave * 512;                 \
    u16* dB = sh + 8192 + (buf)*4096 + wave * 512;          \
    GL16(gA + (k0), dA);                                    \
    GL16(gA + 64 * NN + (k0), dA + 2048);                   \
    GL16(gB + (k0), dB);                                    \
    GL16(gB + 64 * NN + (k0), dB + 2048);                   \
  }

#define SQ_COMPUTE(buf)                                                      \
  {                                                                          \
    const u16* bA = sh + (buf)*4096;                                         \
    const u16* bB = sh + 8192 + (buf)*4096;                                  \
    bfx8 af[4], bf[4];                                                       \
    _Pragma("unroll") for (int m = 0; m < 4; ++m)                            \
        af[m] = *(const bfx8*)&bA[(wr * 64 + m * 16 + l16) * 32 + rot];      \
    _Pragma("unroll") for (int n = 0; n < 4; ++n)                            \
        bf[n] = *(const bfx8*)&bB[(wc * 64 + n * 16 + l16) * 32 + rot];      \
    _Pragma("unroll") for (int m = 0; m < 4; ++m)                            \
        _Pragma("unroll") for (int n = 0; n < 4; ++n)                        \
            acc[m][n] = __builtin_amdgcn_mfma_f32_16x16x32_bf16(             \
                af[m], bf[n], acc[m][n], 0, 0, 0);                           \
  }

  SQ_STAGE(0, 0);
  __syncthreads();
#pragma unroll 2
  for (int t = 1; t < 32; ++t) {
    SQ_STAGE(t * 32, t & 1);                 // prefetch next tile
    __builtin_amdgcn_sched_barrier(0);       // pin load issue before reads
    SQ_COMPUTE((t - 1) & 1);                 // compute current tile
    __syncthreads();                         // drains vmcnt -> next ready
  }
  SQ_COMPUTE(1);

  // C + psi (f32 subtract from accumulator, bf16 store)
#pragma unroll
  for (int m = 0; m < 4; ++m) {
    int row0 = bm + wr * 64 + m * 16 + lk * 4;
#pragma unroll
    for (int n = 0; n < 4; ++n) {
      int col = bn + wc * 64 + n * 16 + l16;
#pragma unroll
      for (int r = 0; r < 4; ++r) {
        size_t idx = (size_t)(row0 + r) * NN + col;
        float v = acc[m][n][r];
        C[idx] = f2b(v);
        Psi[idx] = f2b(v - b2f(Old[idx]));
      }
    }
  }

  // C^T via per-wave LDS bounce: 4 passes of 16 out-rows, 16B stores
  if (offT >= 0) {
    u16* T = (u16*)(base + offT);
    u16* reg = sh + wave * 1152;  // [16][72] u16, 16B-aligned rows
#pragma unroll
    for (int n = 0; n < 4; ++n) {
      __syncthreads();
#pragma unroll
      for (int m = 0; m < 4; ++m) {
        u16x4 pk = {f2b(acc[m][n][0]), f2b(acc[m][n][1]),
                    f2b(acc[m][n][2]), f2b(acc[m][n][3])};
        *(u16x4*)&reg[l16 * 72 + m * 16 + lk * 4] = pk;
      }
      __syncthreads();
#pragma unroll
      for (int h = 0; h < 2; ++h) {
        int row = (lane >> 3) + 8 * h;
        int c8 = lane & 7;
        uint4 v = *(const uint4*)&reg[row * 72 + c8 * 8];
        *(uint4*)&T[(size_t)(bn + wc * 64 + n * 16 + row) * NN + bm + wr * 64 + c8 * 8] = v;
      }
    }
  }
}

// ---- feature GEMM: [1024x64] = A[1024x1024] @ B (Bt [64][1024]).
// V=0: A=psi_sub, B=XT  -> scT_sub + pool(1+sub)
// V=1: A=P8,      B=XT  -> U (f32) + UT
// V=2: A=P8,      B=UT  -> pool F0 (k=0); sc3=|acc-U| -> scT3 + pool(4)
// V=3: A=psi_j,   B=scT_i -> pool(5+pair)
template <int V>
__global__ __launch_bounds__(256)
void k_feat(char* ws, int sliceBase, float* __restrict__ pooled) {
  __shared__ u16 sh[12288];  // 24KB: lA[2][4096] @0 | lB[2][2048] @8192
  unsigned nwg = gridDim.x, wg = blockIdx.x;
  unsigned newid = (wg & 7) * (nwg >> 3) + (wg >> 3);
  int by = newid & 7;
  int zz = newid >> 3;
  int s, sub;
  if (V == 0)      { s = zz / 3; sub = zz % 3; }
  else if (V == 3) { s = zz / 6; sub = zz % 6; }
  else             { s = zz;     sub = 0;     }
  char* base = ws + SLICE0 + (size_t)s * PS_BYTES;

  const u16* A;
  const u16* Bt;
  int kidx = 0;
  if (V == 0) {
    A = (const u16*)(base + OFF_PSI0 + (size_t)sub * MB2);
    Bt = (const u16*)(base + OFF_XT);
    kidx = 1 + sub;
  } else if (V == 1) {
    A = (const u16*)(base + OFF_R0);
    Bt = (const u16*)(base + OFF_XT);
  } else if (V == 2) {
    A = (const u16*)(base + OFF_R0);
    Bt = (const u16*)(base + OFF_UT);
  } else {
    int ii = (sub >= 3) ? 3 : (sub >= 1 ? 2 : 1);
    int jj = sub - (ii * (ii - 1)) / 2;
    A = (const u16*)(base + OFF_PSI0 + (size_t)jj * MB2);
    Bt = (const u16*)(base + OFF_SCT + (size_t)ii * 131072u);
    kidx = 5 + sub;
  }
  float* U = (float*)(base + OFF_U);
  u16* UT = (u16*)(base + OFF_UT);
  u16* scT = (u16*)(base + OFF_SCT + (size_t)(V == 0 ? sub : 3) * 131072u);
  int poolBase = (sliceBase + s) * (KFEAT * FF);

  const int tid = threadIdx.x;
  const int lane = tid & 63, wave = tid >> 6;
  const int wr = wave >> 1, wc = wave & 1;
  const int l16 = lane & 15, lk = lane >> 4;
  const int bm = by * 128;

  const int pc = (((tid & 3) - (tid >> 3)) & 3) << 3;
  const u16* gA = A + (size_t)(bm + (tid >> 2)) * NN + pc;
  const u16* gB = Bt + (size_t)(tid >> 2) * NN + pc;
  const int rot = ((lk + (l16 >> 1)) & 3) << 3;

  f32x4 acc[4][2] = {};

#define FT_STAGE(k0, buf)                                   \
  {                                                         \
    u16* dA = sh + (buf)*4096 + wave * 512;                 \
    u16* dB = sh + 8192 + (buf)*2048 + wave * 512;          \
    GL16(gA + (k0), dA);                                    \
    GL16(gA + 64 * NN + (k0), dA + 2048);                   \
    GL16(gB + (k0), dB);                                    \
  }

#define FT_COMPUTE(buf)                                                      \
  {                                                                          \
    const u16* bA = sh + (buf)*4096;                                         \
    const u16* bB = sh + 8192 + (buf)*2048;                                  \
    bfx8 af[4], bfr[2];                                                      \
    _Pragma("unroll") for (int m = 0; m < 4; ++m)                            \
        af[m] = *(const bfx8*)&bA[(wr * 64 + m * 16 + l16) * 32 + rot];      \
    _Pragma("unroll") for (int n = 0; n < 2; ++n)                            \
        bfr[n] = *(const bfx8*)&bB[(wc * 32 + n * 16 + l16) * 32 + rot];     \
    _Pragma("unroll") for (int m = 0; m < 4; ++m)                            \
        _Pragma("unroll") for (int n = 0; n < 2; ++n)                        \
            acc[m][n] = __builtin_amdgcn_mfma_f32_16x16x32_bf16(             \
                af[m], bfr[n], acc[m][n], 0, 0, 0);                          \
  }

  FT_STAGE(0, 0);
  __syncthreads();
#pragma unroll 2
  for (int t = 1; t < 32; ++t) {
    FT_STAGE(t * 32, t & 1);
    __builtin_amdgcn_sched_barrier(0);
    FT_COMPUTE((t - 1) & 1);
    __syncthreads();
  }
  FT_COMPUTE(1);

  float ps[2] = {0.f, 0.f};
  float psF0[2] = {0.f, 0.f};

#pragma unroll
  for (int m = 0; m < 4; ++m) {
    int row0 = bm + wr * 64 + m * 16 + lk * 4;
#pragma unroll
    for (int n = 0; n < 2; ++n) {
      int col = wc * 32 + n * 16 + l16;
      float v0 = acc[m][n][0], v1 = acc[m][n][1], v2 = acc[m][n][2], v3 = acc[m][n][3];
      if (V == 0 || V == 3) {
        v0 = fabsf(v0); v1 = fabsf(v1); v2 = fabsf(v2); v3 = fabsf(v3);
        ps[n] += v0 + v1 + v2 + v3;
        if (V == 0) {
          u16x4 pk = {f2b(v0), f2b(v1), f2b(v2), f2b(v3)};
          *(u16x4*)&scT[(size_t)col * NN + row0] = pk;
        }
      } else if (V == 1) {
        U[(size_t)(row0 + 0) * FF + col] = v0;
        U[(size_t)(row0 + 1) * FF + col] = v1;
        U[(size_t)(row0 + 2) * FF + col] = v2;
        U[(size_t)(row0 + 3) * FF + col] = v3;
        u16x4 pk = {f2b(v0), f2b(v1), f2b(v2), f2b(v3)};
        *(u16x4*)&UT[(size_t)col * NN + row0] = pk;
      } else {  // V == 2
        psF0[n] += v0 + v1 + v2 + v3;
        float u0 = U[(size_t)(row0 + 0) * FF + col];
        float u1 = U[(size_t)(row0 + 1) * FF + col];
        float u2 = U[(size_t)(row0 + 2) * FF + col];
        float u3 = U[(size_t)(row0 + 3) * FF + col];
        float d0 = fabsf(v0 - u0), d1 = fabsf(v1 - u1);
        float d2 = fabsf(v2 - u2), d3 = fabsf(v3 - u3);
        ps[n] += d0 + d1 + d2 + d3;
        u16x4 pk = {f2b(d0), f2b(d1), f2b(d2), f2b(d3)};
        *(u16x4*)&scT[(size_t)col * NN + row0] = pk;
      }
    }
  }

  if (V != 1) {
#pragma unroll
    for (int n = 0; n < 2; ++n) {
      float v = ps[n];
      v += __shfl_xor(v, 16);
      v += __shfl_xor(v, 32);
      if (lane < 16) {
        int kk = (V == 2) ? 4 : kidx;
        atomicAdd(&pooled[poolBase + kk * FF + wc * 32 + n * 16 + lane], v);
      }
      if (V == 2) {
        float f = psF0[n];
        f += __shfl_xor(f, 16);
        f += __shfl_xor(f, 32);
        if (lane < 16)
          atomicAdd(&pooled[poolBase + 0 * FF + wc * 32 + n * 16 + lane], f);
      }
    }
  }
}

__global__ void k_final(const float* __restrict__ pooled, const float* __restrict__ msum,
                        float* __restrict__ out, int total) {
  int i = blockIdx.x * 256 + threadIdx.x;
  if (i < total) out[i] = pooled[i] / msum[i / (KFEAT * FF)];
}

extern "C" void kernel_launch(void* const* d_in, const int* in_sizes, int n_in,
                              void* d_out, int out_size, void* d_ws, size_t ws_size,
                              hipStream_t stream) {
  const float* P = (const float*)d_in[0];
  const float* X = (const float*)d_in[1];
  const float* mask = (const float*)d_in[2];
  float* out = (float*)d_out;
  char* ws = (char*)d_ws;
  float* pooled = (float*)ws;
  float* msum = (float*)(ws + MSUM_OFF);

  hipMemsetAsync(pooled, 0, POOL_BYTES, stream);
  k_msum<<<NSLICE, 256, 0, stream>>>(mask, msum);

  int S = 1;
  if (ws_size > SLICE0 + PS_BYTES) S = (int)((ws_size - SLICE0) / PS_BYTES);
  if (S > NSLICE) S = NSLICE;
  if (S < 1) S = 1;

  for (int b0 = 0; b0 < NSLICE; b0 += S) {
    int n = (NSLICE - b0 < S) ? (NSLICE - b0) : S;
    k_convP<<<dim3(16, 16, n), 256, 0, stream>>>(P, ws, b0);
    k_convX<<<dim3(16, 1, n), 256, 0, stream>>>(X, ws, b0);
    // P2 = P@P -> R1, psi0 -> PSI0, P2^T -> PSI2 (scratch until sq2)
    k_square<<<64 * n, 256, 0, stream>>>(ws, OFF_R0, OFF_T, OFF_R1, OFF_R0, OFF_PSI0, (int)OFF_PSI2);
    // P4 = P2@P2 -> R2, psi1 -> PSI1, P4^T -> T
    k_square<<<64 * n, 256, 0, stream>>>(ws, OFF_R1, OFF_PSI2, OFF_R2, OFF_R1, OFF_PSI1, (int)OFF_T);
    // P8 = P4@P4 -> R0, psi2 -> PSI2 (overwrites dead P2^T)
    k_square<<<64 * n, 256, 0, stream>>>(ws, OFF_R2, OFF_T, OFF_R0, OFF_R2, OFF_PSI2, -1);
    // sc_i = |psi_i X| ; U = P8 X ; P8 U (F0 + sc3) ; F2 pairs
    k_feat<0><<<24 * n, 256, 0, stream>>>(ws, b0, pooled);
    k_feat<1><<<8 * n, 256, 0, stream>>>(ws, b0, pooled);
    k_feat<2><<<8 * n, 256, 0, stream>>>(ws, b0, pooled);
    k_feat<3><<<48 * n, 256, 0, stream>>>(ws, b0, pooled);
  }
  int total = NSLICE * KFEAT * FF;
  k_final<<<(total + 255) / 256, 256, 0, stream>>>(pooled, msum, out, total);
}

// Round 5
// 627.766 us; speedup vs baseline: 1.2037x; 1.0289x over previous
//
#include <hip/hip_runtime.h>

typedef unsigned short u16;
typedef __bf16 bfx8 __attribute__((ext_vector_type(8)));
typedef float f32x4 __attribute__((ext_vector_type(4)));
typedef unsigned short u16x4 __attribute__((ext_vector_type(4)));

#define NN 1024
#define FF 64
#define NSLICE 32
#define KFEAT 11

// ---- workspace layout ----
#define POOL_BYTES (NSLICE * KFEAT * FF * 4)  // 90112
#define MSUM_OFF   POOL_BYTES
#define SLICE0     ((size_t)1 << 20)
#define MB2        (2u * 1024u * 1024u)
#define OFF_R0     0u
#define OFF_R1     (1u * MB2)
#define OFF_R2     (2u * MB2)
#define OFF_T      (3u * MB2)
#define OFF_PSI0   (4u * MB2)
#define OFF_PSI1   (5u * MB2)
#define OFF_PSI2   (6u * MB2)
#define OFF_XT     (7u * MB2)                    // 128KB  bf16 [64][1024]
#define OFF_SCT    (7u * MB2 + 131072u)          // 4x128KB bf16 [64][1024]
#define OFF_U      (7u * MB2 + 131072u * 5u)     // 256KB  f32 [1024][64]
#define OFF_UT     (7u * MB2 + 131072u * 7u)     // 128KB  bf16 [64][1024]
#define PS_BYTES   ((size_t)(7u * MB2 + 131072u * 8u))  // 15728640

// async global->LDS, 16B per lane; LDS dest = wave-uniform base + lane*16
#define GL16(g, l) __builtin_amdgcn_global_load_lds( \
    (const __attribute__((address_space(1))) unsigned int*)(g), \
    (__attribute__((address_space(3))) unsigned int*)(l), 16, 0, 0)

// Bank-conflict-free chunk rotation (rule #21): linear LDS dest, permuted
// global source chunk (c - (tid>>3))&3, matching permuted read rotation
// ((lk + (l16>>1))&3). Verified: conflict counter 9.17M -> 0.79M.

__device__ __forceinline__ u16 f2b(float v) {
  __bf16 h = (__bf16)v;
  return __builtin_bit_cast(u16, h);
}
__device__ __forceinline__ float b2f(u16 u) {
  return (float)__builtin_bit_cast(__bf16, u);
}

// ---- P slice: f32 -> bf16 row-major (R0) + bf16 transposed (T) ----
__global__ void k_convP(const float* __restrict__ P, char* ws, int sliceBase) {
  __shared__ float tile[64][65];
  int s = blockIdx.z;
  const float* Ps = P + (size_t)(sliceBase + s) * NN * NN;
  char* base = ws + SLICE0 + (size_t)s * PS_BYTES;
  u16* Pb  = (u16*)(base + OFF_R0);
  u16* PbT = (u16*)(base + OFF_T);
  int r0 = blockIdx.y * 64, c0 = blockIdx.x * 64;
  int tid = threadIdx.x;
  int tc = tid & 15, tr = tid >> 4;
  for (int rr = 0; rr < 64; rr += 16) {
    int r = rr + tr;
    float4 v = *(const float4*)&Ps[(size_t)(r0 + r) * NN + c0 + tc * 4];
    tile[r][tc * 4 + 0] = v.x;
    tile[r][tc * 4 + 1] = v.y;
    tile[r][tc * 4 + 2] = v.z;
    tile[r][tc * 4 + 3] = v.w;
    u16x4 pk = {f2b(v.x), f2b(v.y), f2b(v.z), f2b(v.w)};
    *(u16x4*)&Pb[(size_t)(r0 + r) * NN + c0 + tc * 4] = pk;
  }
  __syncthreads();
  for (int it = 0; it < 4; ++it) {
    int oc = (tid >> 4) + it * 16;
    int ch = tid & 15;
    u16x4 pk = {f2b(tile[ch * 4 + 0][oc]), f2b(tile[ch * 4 + 1][oc]),
                f2b(tile[ch * 4 + 2][oc]), f2b(tile[ch * 4 + 3][oc])};
    *(u16x4*)&PbT[(size_t)(c0 + oc) * NN + r0 + ch * 4] = pk;
  }
}

// ---- X slice: f32 [1024][64] -> bf16 XT [64][1024] ----
__global__ void k_convX(const float* __restrict__ X, char* ws, int sliceBase) {
  __shared__ float tile[64][65];
  int s = blockIdx.z;
  const float* Xs = X + (size_t)(sliceBase + s) * NN * FF;
  u16* XT = (u16*)(ws + SLICE0 + (size_t)s * PS_BYTES + OFF_XT);
  int r0 = blockIdx.x * 64;
  int tx = threadIdx.x & 63, ty = threadIdx.x >> 6;
  for (int rr = 0; rr < 64; rr += 4)
    tile[rr + ty][tx] = Xs[(size_t)(r0 + rr + ty) * FF + tx];
  __syncthreads();
  for (int rr = 0; rr < 64; rr += 4)
    XT[(size_t)(rr + ty) * NN + r0 + tx] = f2b(tile[tx][rr + ty]);
}

__global__ void k_msum(const float* __restrict__ mask, float* msum) {
  int s = blockIdx.x;
  const float* m = mask + (size_t)s * NN;
  int t = threadIdx.x;
  float v = m[t] + m[t + 256] + m[t + 512] + m[t + 768];
  for (int o = 32; o; o >>= 1) v += __shfl_down(v, o);
  __shared__ float ps[4];
  if ((t & 63) == 0) ps[t >> 6] = v;
  __syncthreads();
  if (t == 0) msum[s] = ps[0] + ps[1] + ps[2] + ps[3];
}

// ---- squaring GEMM: C = A @ B (B given transposed). Writes newP bf16,
// psi = newP - oldP (f32 subtract), optionally C^T (offT>=0).
// 256x256 tile, BK=32, 8 waves (2Mx4N, per-wave 128x64), global_load_lds,
// XCD swizzle, chunk-rotation LDS, COUNTED-vmcnt double-buffer pipeline:
// per K-step {STAGE t+1; vmcnt(4)=own tile-t loads done; s_barrier;
// ds_read+MFMA on t; s_barrier}. Tile t+1's loads stay in flight across
// both barriers (T4). Tail drains vmcnt(0) once.
__global__ __launch_bounds__(512, 2)
void k_square(char* ws, int offA, int offB, int offC, int offOld, int offPsi,
              int offT) {
  __shared__ u16 sh[32768];  // 64KB: buf b: A @ b*16384, B @ b*16384+8192

  unsigned nwg = gridDim.x, wg = blockIdx.x;
  unsigned newid = (wg & 7) * (nwg >> 3) + (wg >> 3);  // slices grouped per XCD
  int z = newid >> 4;
  int by = (newid >> 2) & 3, bx = newid & 3;

  char* base = ws + SLICE0 + (size_t)z * PS_BYTES;
  const u16* A   = (const u16*)(base + offA);
  const u16* Bt  = (const u16*)(base + offB);
  u16* C         = (u16*)(base + offC);
  const u16* Old = (const u16*)(base + offOld);
  u16* Psi       = (u16*)(base + offPsi);

  const int tid = threadIdx.x;
  const int lane = tid & 63, wave = tid >> 6;   // 8 waves
  const int wr = wave >> 2, wc = wave & 3;      // 2 x 4 wave grid
  const int l16 = lane & 15, lk = lane >> 4;
  const int bm = by * 256, bn = bx * 256;

  // staging: wave w covers rows w*32 + j*16 + (lane>>2), permuted chunk
  const int pc = (((lane & 3) - (lane >> 3)) & 3) << 3;
  const u16* gA0 = A + (size_t)(bm + wave * 32 + (lane >> 2)) * NN + pc;
  const u16* gB0 = Bt + (size_t)(bn + wave * 32 + (lane >> 2)) * NN + pc;
  const int rot = ((lk + (l16 >> 1)) & 3) << 3;  // permuted read chunk

  f32x4 acc[8][4] = {};

#define SQ_STAGE(k0, buf)                                   \
  {                                                         \
    u16* dA = sh + (buf)*16384 + wave * 1024;               \
    u16* dB = sh + (buf)*16384 + 8192 + wave * 1024;        \
    GL16(gA0 + (k0), dA);                                   \
    GL16(gA0 + 16 * NN + (k0), dA + 512);                   \
    GL16(gB0 + (k0), dB);                                   \
    GL16(gB0 + 16 * NN + (k0), dB + 512);                   \
  }

#define SQ_COMPUTE(buf)                                                      \
  {                                                                          \
    const u16* bA = sh + (buf)*16384;                                        \
    const u16* bB = sh + (buf)*16384 + 8192;                                 \
    bfx8 af[8], bf[4];                                                       \
    _Pragma("unroll") for (int m = 0; m < 8; ++m)                            \
        af[m] = *(const bfx8*)&bA[(wr * 128 + m * 16 + l16) * 32 + rot];     \
    _Pragma("unroll") for (int n = 0; n < 4; ++n)                            \
        bf[n] = *(const bfx8*)&bB[(wc * 64 + n * 16 + l16) * 32 + rot];      \
    __builtin_amdgcn_s_setprio(1);                                           \
    _Pragma("unroll") for (int m = 0; m < 8; ++m)                            \
        _Pragma("unroll") for (int n = 0; n < 4; ++n)                        \
            acc[m][n] = __builtin_amdgcn_mfma_f32_16x16x32_bf16(             \
                af[m], bf[n], acc[m][n], 0, 0, 0);                           \
    __builtin_amdgcn_s_setprio(0);                                           \
  }

  SQ_STAGE(0, 0);
#pragma unroll 2
  for (int t = 1; t < 32; ++t) {
    SQ_STAGE(t * 32, t & 1);                       // tile t -> buf t&1
    asm volatile("s_waitcnt vmcnt(4)" ::: "memory");  // own tile t-1 loads done
    __builtin_amdgcn_s_barrier();                  // -> globally done
    SQ_COMPUTE((t - 1) & 1);
    __builtin_amdgcn_s_barrier();                  // reads done, buf reusable
  }
  asm volatile("s_waitcnt vmcnt(0)" ::: "memory");
  __builtin_amdgcn_s_barrier();
  SQ_COMPUTE(1);

  // C + psi (f32 subtract from accumulator, bf16 store)
#pragma unroll
  for (int m = 0; m < 8; ++m) {
    int row0 = bm + wr * 128 + m * 16 + lk * 4;
#pragma unroll
    for (int n = 0; n < 4; ++n) {
      int col = bn + wc * 64 + n * 16 + l16;
#pragma unroll
      for (int r = 0; r < 4; ++r) {
        size_t idx = (size_t)(row0 + r) * NN + col;
        float v = acc[m][n][r];
        C[idx] = f2b(v);
        Psi[idx] = f2b(v - b2f(Old[idx]));
      }
    }
  }

  // C^T via per-wave LDS bounce: 4 passes (one per n-frag), 16B stores
  if (offT >= 0) {
    u16* T = (u16*)(base + offT);
    u16* reg = sh + wave * 2176;  // [16][136] u16 per wave
#pragma unroll
    for (int n = 0; n < 4; ++n) {
      __syncthreads();
#pragma unroll
      for (int m = 0; m < 8; ++m) {
        u16x4 pk = {f2b(acc[m][n][0]), f2b(acc[m][n][1]),
                    f2b(acc[m][n][2]), f2b(acc[m][n][3])};
        *(u16x4*)&reg[l16 * 136 + m * 16 + lk * 4] = pk;
      }
      __syncthreads();
#pragma unroll
      for (int h = 0; h < 4; ++h) {
        int row = lane >> 2;            // 0..15 (C column within n-frag)
        int c8 = (lane & 3) + h * 4;    // 16 chunks of 8 u16
        uint4 v = *(const uint4*)&reg[row * 136 + c8 * 8];
        *(uint4*)&T[(size_t)(bn + wc * 64 + n * 16 + row) * NN + bm + wr * 128 + c8 * 8] = v;
      }
    }
  }
}

// ---- feature GEMM: [1024x64] = A[1024x1024] @ B (Bt [64][1024]).
// V=0: A=psi_sub, B=XT  -> scT_sub + pool(1+sub)
// V=1: A=P8,      B=XT  -> U (f32) + UT
// V=2: A=P8,      B=UT  -> pool F0 (k=0); sc3=|acc-U| -> scT3 + pool(4)
// V=3: A=psi_j,   B=scT_i -> pool(5+pair)
// Counted-vmcnt pipeline (3 GL16/wave/tile -> vmcnt(3)).
template <int V>
__global__ __launch_bounds__(256)
void k_feat(char* ws, int sliceBase, float* __restrict__ pooled) {
  __shared__ u16 sh[12288];  // 24KB: lA[2][4096] @0 | lB[2][2048] @8192
  unsigned nwg = gridDim.x, wg = blockIdx.x;
  unsigned newid = (wg & 7) * (nwg >> 3) + (wg >> 3);
  int by = newid & 7;
  int zz = newid >> 3;
  int s, sub;
  if (V == 0)      { s = zz / 3; sub = zz % 3; }
  else if (V == 3) { s = zz / 6; sub = zz % 6; }
  else             { s = zz;     sub = 0;     }
  char* base = ws + SLICE0 + (size_t)s * PS_BYTES;

  const u16* A;
  const u16* Bt;
  int kidx = 0;
  if (V == 0) {
    A = (const u16*)(base + OFF_PSI0 + (size_t)sub * MB2);
    Bt = (const u16*)(base + OFF_XT);
    kidx = 1 + sub;
  } else if (V == 1) {
    A = (const u16*)(base + OFF_R0);
    Bt = (const u16*)(base + OFF_XT);
  } else if (V == 2) {
    A = (const u16*)(base + OFF_R0);
    Bt = (const u16*)(base + OFF_UT);
  } else {
    int ii = (sub >= 3) ? 3 : (sub >= 1 ? 2 : 1);
    int jj = sub - (ii * (ii - 1)) / 2;
    A = (const u16*)(base + OFF_PSI0 + (size_t)jj * MB2);
    Bt = (const u16*)(base + OFF_SCT + (size_t)ii * 131072u);
    kidx = 5 + sub;
  }
  float* U = (float*)(base + OFF_U);
  u16* UT = (u16*)(base + OFF_UT);
  u16* scT = (u16*)(base + OFF_SCT + (size_t)(V == 0 ? sub : 3) * 131072u);
  int poolBase = (sliceBase + s) * (KFEAT * FF);

  const int tid = threadIdx.x;
  const int lane = tid & 63, wave = tid >> 6;
  const int wr = wave >> 1, wc = wave & 1;
  const int l16 = lane & 15, lk = lane >> 4;
  const int bm = by * 128;

  const int pc = (((tid & 3) - (tid >> 3)) & 3) << 3;
  const u16* gA = A + (size_t)(bm + (tid >> 2)) * NN + pc;
  const u16* gB = Bt + (size_t)(tid >> 2) * NN + pc;
  const int rot = ((lk + (l16 >> 1)) & 3) << 3;

  f32x4 acc[4][2] = {};

#define FT_STAGE(k0, buf)                                   \
  {                                                         \
    u16* dA = sh + (buf)*4096 + wave * 512;                 \
    u16* dB = sh + 8192 + (buf)*2048 + wave * 512;          \
    GL16(gA + (k0), dA);                                    \
    GL16(gA + 64 * NN + (k0), dA + 2048);                   \
    GL16(gB + (k0), dB);                                    \
  }

#define FT_COMPUTE(buf)                                                      \
  {                                                                          \
    const u16* bA = sh + (buf)*4096;                                         \
    const u16* bB = sh + 8192 + (buf)*2048;                                  \
    bfx8 af[4], bfr[2];                                                      \
    _Pragma("unroll") for (int m = 0; m < 4; ++m)                            \
        af[m] = *(const bfx8*)&bA[(wr * 64 + m * 16 + l16) * 32 + rot];      \
    _Pragma("unroll") for (int n = 0; n < 2; ++n)                            \
        bfr[n] = *(const bfx8*)&bB[(wc * 32 + n * 16 + l16) * 32 + rot];     \
    __builtin_amdgcn_s_setprio(1);                                           \
    _Pragma("unroll") for (int m = 0; m < 4; ++m)                            \
        _Pragma("unroll") for (int n = 0; n < 2; ++n)                        \
            acc[m][n] = __builtin_amdgcn_mfma_f32_16x16x32_bf16(             \
                af[m], bfr[n], acc[m][n], 0, 0, 0);                          \
    __builtin_amdgcn_s_setprio(0);                                           \
  }

  FT_STAGE(0, 0);
#pragma unroll 2
  for (int t = 1; t < 32; ++t) {
    FT_STAGE(t * 32, t & 1);
    asm volatile("s_waitcnt vmcnt(3)" ::: "memory");
    __builtin_amdgcn_s_barrier();
    FT_COMPUTE((t - 1) & 1);
    __builtin_amdgcn_s_barrier();
  }
  asm volatile("s_waitcnt vmcnt(0)" ::: "memory");
  __builtin_amdgcn_s_barrier();
  FT_COMPUTE(1);

  float ps[2] = {0.f, 0.f};
  float psF0[2] = {0.f, 0.f};

#pragma unroll
  for (int m = 0; m < 4; ++m) {
    int row0 = bm + wr * 64 + m * 16 + lk * 4;
#pragma unroll
    for (int n = 0; n < 2; ++n) {
      int col = wc * 32 + n * 16 + l16;
      float v0 = acc[m][n][0], v1 = acc[m][n][1], v2 = acc[m][n][2], v3 = acc[m][n][3];
      if (V == 0 || V == 3) {
        v0 = fabsf(v0); v1 = fabsf(v1); v2 = fabsf(v2); v3 = fabsf(v3);
        ps[n] += v0 + v1 + v2 + v3;
        if (V == 0) {
          u16x4 pk = {f2b(v0), f2b(v1), f2b(v2), f2b(v3)};
          *(u16x4*)&scT[(size_t)col * NN + row0] = pk;
        }
      } else if (V == 1) {
        U[(size_t)(row0 + 0) * FF + col] = v0;
        U[(size_t)(row0 + 1) * FF + col] = v1;
        U[(size_t)(row0 + 2) * FF + col] = v2;
        U[(size_t)(row0 + 3) * FF + col] = v3;
        u16x4 pk = {f2b(v0), f2b(v1), f2b(v2), f2b(v3)};
        *(u16x4*)&UT[(size_t)col * NN + row0] = pk;
      } else {  // V == 2
        psF0[n] += v0 + v1 + v2 + v3;
        float u0 = U[(size_t)(row0 + 0) * FF + col];
        float u1 = U[(size_t)(row0 + 1) * FF + col];
        float u2 = U[(size_t)(row0 + 2) * FF + col];
        float u3 = U[(size_t)(row0 + 3) * FF + col];
        float d0 = fabsf(v0 - u0), d1 = fabsf(v1 - u1);
        float d2 = fabsf(v2 - u2), d3 = fabsf(v3 - u3);
        ps[n] += d0 + d1 + d2 + d3;
        u16x4 pk = {f2b(d0), f2b(d1), f2b(d2), f2b(d3)};
        *(u16x4*)&scT[(size_t)col * NN + row0] = pk;
      }
    }
  }

  if (V != 1) {
#pragma unroll
    for (int n = 0; n < 2; ++n) {
      float v = ps[n];
      v += __shfl_xor(v, 16);
      v += __shfl_xor(v, 32);
      if (lane < 16) {
        int kk = (V == 2) ? 4 : kidx;
        atomicAdd(&pooled[poolBase + kk * FF + wc * 32 + n * 16 + lane], v);
      }
      if (V == 2) {
        float f = psF0[n];
        f += __shfl_xor(f, 16);
        f += __shfl_xor(f, 32);
        if (lane < 16)
          atomicAdd(&pooled[poolBase + 0 * FF + wc * 32 + n * 16 + lane], f);
      }
    }
  }
}

__global__ void k_final(const float* __restrict__ pooled, const float* __restrict__ msum,
                        float* __restrict__ out, int total) {
  int i = blockIdx.x * 256 + threadIdx.x;
  if (i < total) out[i] = pooled[i] / msum[i / (KFEAT * FF)];
}

extern "C" void kernel_launch(void* const* d_in, const int* in_sizes, int n_in,
                              void* d_out, int out_size, void* d_ws, size_t ws_size,
                              hipStream_t stream) {
  const float* P = (const float*)d_in[0];
  const float* X = (const float*)d_in[1];
  const float* mask = (const float*)d_in[2];
  float* out = (float*)d_out;
  char* ws = (char*)d_ws;
  float* pooled = (float*)ws;
  float* msum = (float*)(ws + MSUM_OFF);

  hipMemsetAsync(pooled, 0, POOL_BYTES, stream);
  k_msum<<<NSLICE, 256, 0, stream>>>(mask, msum);

  int S = 1;
  if (ws_size > SLICE0 + PS_BYTES) S = (int)((ws_size - SLICE0) / PS_BYTES);
  if (S > NSLICE) S = NSLICE;
  if (S < 1) S = 1;

  for (int b0 = 0; b0 < NSLICE; b0 += S) {
    int n = (NSLICE - b0 < S) ? (NSLICE - b0) : S;
    k_convP<<<dim3(16, 16, n), 256, 0, stream>>>(P, ws, b0);
    k_convX<<<dim3(16, 1, n), 256, 0, stream>>>(X, ws, b0);
    // P2 = P@P -> R1, psi0 -> PSI0, P2^T -> PSI2 (scratch until sq2)
    k_square<<<16 * n, 512, 0, stream>>>(ws, OFF_R0, OFF_T, OFF_R1, OFF_R0, OFF_PSI0, (int)OFF_PSI2);
    // P4 = P2@P2 -> R2, psi1 -> PSI1, P4^T -> T
    k_square<<<16 * n, 512, 0, stream>>>(ws, OFF_R1, OFF_PSI2, OFF_R2, OFF_R1, OFF_PSI1, (int)OFF_T);
    // P8 = P4@P4 -> R0, psi2 -> PSI2 (overwrites dead P2^T)
    k_square<<<16 * n, 512, 0, stream>>>(ws, OFF_R2, OFF_T, OFF_R0, OFF_R2, OFF_PSI2, -1);
    // sc_i = |psi_i X| ; U = P8 X ; P8 U (F0 + sc3) ; F2 pairs
    k_feat<0><<<24 * n, 256, 0, stream>>>(ws, b0, pooled);
    k_feat<1><<<8 * n, 256, 0, stream>>>(ws, b0, pooled);
    k_feat<2><<<8 * n, 256, 0, stream>>>(ws, b0, pooled);
    k_feat<3><<<48 * n, 256, 0, stream>>>(ws, b0, pooled);
  }
  int total = NSLICE * KFEAT * FF;
  k_final<<<(total + 255) / 256, 256, 0, stream>>>(pooled, msum, out, total);
}

// Round 6
// 481.751 us; speedup vs baseline: 1.5685x; 1.3031x over previous
//
#include <hip/hip_runtime.h>

typedef unsigned short u16;
typedef __bf16 bfx8 __attribute__((ext_vector_type(8)));
typedef float f32x4 __attribute__((ext_vector_type(4)));
typedef unsigned short u16x4 __attribute__((ext_vector_type(4)));

#define NN 1024
#define FF 64
#define NSLICE 32
#define KFEAT 11

// ---- workspace layout ----
#define POOL_BYTES (NSLICE * KFEAT * FF * 4)  // 90112
#define MSUM_OFF   POOL_BYTES
#define SLICE0     ((size_t)1 << 20)
#define MB1        (1024u * 1024u)
#define KB128      (131072u)
#define KB256      (262144u)
// bf16 NxN matrices
#define OFF_P    0u
#define OFF_PT   (2u * MB1)
#define OFF_P2   (4u * MB1)
#define OFF_P2T  (6u * MB1)
#define OFF_P4   (8u * MB1)
// bf16 [64][1024] transposed narrow operands
#define OFF_XT   (10u * MB1)
#define OFF_Y4T  (10u * MB1 + 1u * KB128)
#define OFF_Y8T  (10u * MB1 + 2u * KB128)
#define OFF_Y12T (10u * MB1 + 3u * KB128)
#define OFF_S1T  (10u * MB1 + 4u * KB128)
#define OFF_S2T  (10u * MB1 + 5u * KB128)
#define OFF_S3T  (10u * MB1 + 6u * KB128)
#define OFF_WT   (10u * MB1 + 7u * KB128)
// f32 [1024][64] narrow results
#define OFF_Y1   (11u * MB1)
#define OFF_Y2   (11u * MB1 + 1u * KB256)
#define OFF_Y4   (11u * MB1 + 2u * KB256)
#define OFF_Y8   (11u * MB1 + 3u * KB256)
#define OFF_PS1  (11u * MB1 + 4u * KB256)
#define OFF_PS2  (11u * MB1 + 5u * KB256)
#define OFF_PS3  (11u * MB1 + 6u * KB256)
#define OFF_QS1  (11u * MB1 + 7u * KB256)
#define OFF_QS2  (11u * MB1 + 8u * KB256)
#define OFF_QS3  (11u * MB1 + 9u * KB256)
#define OFF_W    (11u * MB1 + 10u * KB256)
#define PS_BYTES ((size_t)(14u * MB1))

// async global->LDS, 16B per lane; LDS dest = wave-uniform base + lane*16
#define GL16(g, l) __builtin_amdgcn_global_load_lds( \
    (const __attribute__((address_space(1))) unsigned int*)(g), \
    (__attribute__((address_space(3))) unsigned int*)(l), 16, 0, 0)

// Bank-conflict-free chunk rotation (rule #21): linear LDS dest, permuted
// global source chunk (c - (tid>>3))&3, matching permuted read rotation
// ((lk + (l16>>1))&3). Verified: conflict counter 9.17M -> 0.79M.

__device__ __forceinline__ u16 f2b(float v) {
  __bf16 h = (__bf16)v;
  return __builtin_bit_cast(u16, h);
}

// ---- P slice: f32 -> bf16 row-major (P) + bf16 transposed (PT) ----
__global__ void k_convP(const float* __restrict__ P, char* ws, int sliceBase) {
  __shared__ float tile[64][65];
  int s = blockIdx.z;
  const float* Ps = P + (size_t)(sliceBase + s) * NN * NN;
  char* base = ws + SLICE0 + (size_t)s * PS_BYTES;
  u16* Pb  = (u16*)(base + OFF_P);
  u16* PbT = (u16*)(base + OFF_PT);
  int r0 = blockIdx.y * 64, c0 = blockIdx.x * 64;
  int tid = threadIdx.x;
  int tc = tid & 15, tr = tid >> 4;
  for (int rr = 0; rr < 64; rr += 16) {
    int r = rr + tr;
    float4 v = *(const float4*)&Ps[(size_t)(r0 + r) * NN + c0 + tc * 4];
    tile[r][tc * 4 + 0] = v.x;
    tile[r][tc * 4 + 1] = v.y;
    tile[r][tc * 4 + 2] = v.z;
    tile[r][tc * 4 + 3] = v.w;
    u16x4 pk = {f2b(v.x), f2b(v.y), f2b(v.z), f2b(v.w)};
    *(u16x4*)&Pb[(size_t)(r0 + r) * NN + c0 + tc * 4] = pk;
  }
  __syncthreads();
  for (int it = 0; it < 4; ++it) {
    int oc = (tid >> 4) + it * 16;
    int ch = tid & 15;
    u16x4 pk = {f2b(tile[ch * 4 + 0][oc]), f2b(tile[ch * 4 + 1][oc]),
                f2b(tile[ch * 4 + 2][oc]), f2b(tile[ch * 4 + 3][oc])};
    *(u16x4*)&PbT[(size_t)(c0 + oc) * NN + r0 + ch * 4] = pk;
  }
}

// ---- X slice: f32 [1024][64] -> bf16 XT [64][1024] ----
__global__ void k_convX(const float* __restrict__ X, char* ws, int sliceBase) {
  __shared__ float tile[64][65];
  int s = blockIdx.z;
  const float* Xs = X + (size_t)(sliceBase + s) * NN * FF;
  u16* XT = (u16*)(ws + SLICE0 + (size_t)s * PS_BYTES + OFF_XT);
  int r0 = blockIdx.x * 64;
  int tx = threadIdx.x & 63, ty = threadIdx.x >> 6;
  for (int rr = 0; rr < 64; rr += 4)
    tile[rr + ty][tx] = Xs[(size_t)(r0 + rr + ty) * FF + tx];
  __syncthreads();
  for (int rr = 0; rr < 64; rr += 4)
    XT[(size_t)(rr + ty) * NN + r0 + tx] = f2b(tile[tx][rr + ty]);
}

__global__ void k_msum(const float* __restrict__ mask, float* msum) {
  int s = blockIdx.x;
  const float* m = mask + (size_t)s * NN;
  int t = threadIdx.x;
  float v = m[t] + m[t + 256] + m[t + 512] + m[t + 768];
  for (int o = 32; o; o >>= 1) v += __shfl_down(v, o);
  __shared__ float ps[4];
  if ((t & 63) == 0) ps[t >> 6] = v;
  __syncthreads();
  if (t == 0) msum[s] = ps[0] + ps[1] + ps[2] + ps[3];
}

// ---- squaring GEMM: C = A @ B (B given transposed). Writes C bf16 and
// optionally C^T (offT>=0). 128x128 tile, BK=32, 4 waves, global_load_lds,
// XCD swizzle, chunk-rotation LDS, counted-vmcnt double-buffer pipeline.
__global__ __launch_bounds__(256)
void k_square(char* ws, int offA, int offB, int offC, int offT) {
  __shared__ u16 sh[16384];  // 32KB: A bufs @0/4096, B bufs @8192/12288

  unsigned nwg = gridDim.x, wg = blockIdx.x;
  unsigned newid = (wg & 7) * (nwg >> 3) + (wg >> 3);  // slice-per-XCD
  int z = newid >> 6;
  int by = (newid >> 3) & 7, bx = newid & 7;

  char* base = ws + SLICE0 + (size_t)z * PS_BYTES;
  const u16* A  = (const u16*)(base + offA);
  const u16* Bt = (const u16*)(base + offB);
  u16* C        = (u16*)(base + offC);

  const int tid = threadIdx.x;
  const int lane = tid & 63, wave = tid >> 6;
  const int wr = wave >> 1, wc = wave & 1;
  const int l16 = lane & 15, lk = lane >> 4;
  const int bm = by * 128, bn = bx * 128;

  const int pc = (((tid & 3) - (tid >> 3)) & 3) << 3;
  const u16* gA = A + (size_t)(bm + (tid >> 2)) * NN + pc;
  const u16* gB = Bt + (size_t)(bn + (tid >> 2)) * NN + pc;
  const int rot = ((lk + (l16 >> 1)) & 3) << 3;

  f32x4 acc[4][4] = {};

#define SQ_STAGE(k0, buf)                                   \
  {                                                         \
    u16* dA = sh + (buf)*4096 + wave * 512;                 \
    u16* dB = sh + 8192 + (buf)*4096 + wave * 512;          \
    GL16(gA + (k0), dA);                                    \
    GL16(gA + 64 * NN + (k0), dA + 2048);                   \
    GL16(gB + (k0), dB);                                    \
    GL16(gB + 64 * NN + (k0), dB + 2048);                   \
  }

#define SQ_COMPUTE(buf)                                                      \
  {                                                                          \
    const u16* bA = sh + (buf)*4096;                                         \
    const u16* bB = sh + 8192 + (buf)*4096;                                  \
    bfx8 af[4], bf[4];                                                       \
    _Pragma("unroll") for (int m = 0; m < 4; ++m)                            \
        af[m] = *(const bfx8*)&bA[(wr * 64 + m * 16 + l16) * 32 + rot];      \
    _Pragma("unroll") for (int n = 0; n < 4; ++n)                            \
        bf[n] = *(const bfx8*)&bB[(wc * 64 + n * 16 + l16) * 32 + rot];      \
    __builtin_amdgcn_s_setprio(1);                                           \
    _Pragma("unroll") for (int m = 0; m < 4; ++m)                            \
        _Pragma("unroll") for (int n = 0; n < 4; ++n)                        \
            acc[m][n] = __builtin_amdgcn_mfma_f32_16x16x32_bf16(             \
                af[m], bf[n], acc[m][n], 0, 0, 0);                           \
    __builtin_amdgcn_s_setprio(0);                                           \
  }

  SQ_STAGE(0, 0);
#pragma unroll 2
  for (int t = 1; t < 32; ++t) {
    SQ_STAGE(t * 32, t & 1);
    asm volatile("s_waitcnt vmcnt(4)" ::: "memory");  // own tile t-1 done
    __builtin_amdgcn_s_barrier();                     // -> globally done
    SQ_COMPUTE((t - 1) & 1);
    __builtin_amdgcn_s_barrier();                     // reads done
  }
  asm volatile("s_waitcnt vmcnt(0)" ::: "memory");
  __builtin_amdgcn_s_barrier();
  SQ_COMPUTE(1);

  // C store (bf16 scalar)
#pragma unroll
  for (int m = 0; m < 4; ++m) {
    int row0 = bm + wr * 64 + m * 16 + lk * 4;
#pragma unroll
    for (int n = 0; n < 4; ++n) {
      int col = bn + wc * 64 + n * 16 + l16;
#pragma unroll
      for (int r = 0; r < 4; ++r)
        C[(size_t)(row0 + r) * NN + col] = f2b(acc[m][n][r]);
    }
  }

  // C^T via per-wave LDS bounce: 4 passes of 16 out-rows, 16B stores
  if (offT >= 0) {
    u16* T = (u16*)(base + offT);
    u16* reg = sh + wave * 1152;  // [16][72] u16, 16B-aligned rows
#pragma unroll
    for (int n = 0; n < 4; ++n) {
      __syncthreads();
#pragma unroll
      for (int m = 0; m < 4; ++m) {
        u16x4 pk = {f2b(acc[m][n][0]), f2b(acc[m][n][1]),
                    f2b(acc[m][n][2]), f2b(acc[m][n][3])};
        *(u16x4*)&reg[l16 * 72 + m * 16 + lk * 4] = pk;
      }
      __syncthreads();
#pragma unroll
      for (int h = 0; h < 2; ++h) {
        int row = (lane >> 3) + 8 * h;
        int c8 = lane & 7;
        uint4 v = *(const uint4*)&reg[row * 72 + c8 * 8];
        *(uint4*)&T[(size_t)(bn + wc * 64 + n * 16 + row) * NN + bm + wr * 64 + c8 * 8] = v;
      }
    }
  }
}

// ---- unified narrow GEMM: acc[1024x64] = A[1024x1024] @ Bt_sub[64][1024].
// Per sub-batch flags: D (f32 diff source), pool-|w| k, f32 out (v),
// bf16-T out of |w|, bf16-T out of v. rawK pools raw v (F0).
struct NA {
  int a, nsub, rawK;
  int bt0, bt1, bt2;
  int d0, d1, d2;
  int pk0, pk1, pk2;
  int f0, f1, f2;
  int ta0, ta1, ta2;
  int tv0, tv1, tv2;
};

__global__ __launch_bounds__(256)
void k_nar(char* ws, int sliceBase, float* __restrict__ pooled, NA na) {
  __shared__ u16 sh[12288];  // 24KB: A bufs @0/4096, B bufs @8192/10240
  unsigned nwg = gridDim.x, wg = blockIdx.x;
  unsigned newid = (wg & 7) * (nwg >> 3) + (wg >> 3);
  int by = newid & 7;
  int rest = newid >> 3;
  int sub = rest % na.nsub;
  int s = rest / na.nsub;
  char* base = ws + SLICE0 + (size_t)s * PS_BYTES;

  int bt  = sub == 0 ? na.bt0 : (sub == 1 ? na.bt1 : na.bt2);
  int dof = sub == 0 ? na.d0  : (sub == 1 ? na.d1  : na.d2);
  int pk  = sub == 0 ? na.pk0 : (sub == 1 ? na.pk1 : na.pk2);
  int fo  = sub == 0 ? na.f0  : (sub == 1 ? na.f1  : na.f2);
  int tao = sub == 0 ? na.ta0 : (sub == 1 ? na.ta1 : na.ta2);
  int tvo = sub == 0 ? na.tv0 : (sub == 1 ? na.tv1 : na.tv2);

  const u16* A  = (const u16*)(base + na.a);
  const u16* Bt = (const u16*)(base + bt);
  int poolBase = (sliceBase + s) * (KFEAT * FF);

  const int tid = threadIdx.x;
  const int lane = tid & 63, wave = tid >> 6;
  const int wr = wave >> 1, wc = wave & 1;
  const int l16 = lane & 15, lk = lane >> 4;
  const int bm = by * 128;

  const int pc = (((tid & 3) - (tid >> 3)) & 3) << 3;
  const u16* gA = A + (size_t)(bm + (tid >> 2)) * NN + pc;
  const u16* gB = Bt + (size_t)(tid >> 2) * NN + pc;
  const int rot = ((lk + (l16 >> 1)) & 3) << 3;

  f32x4 acc[4][2] = {};

#define FT_STAGE(k0, buf)                                   \
  {                                                         \
    u16* dA = sh + (buf)*4096 + wave * 512;                 \
    u16* dB = sh + 8192 + (buf)*2048 + wave * 512;          \
    GL16(gA + (k0), dA);                                    \
    GL16(gA + 64 * NN + (k0), dA + 2048);                   \
    GL16(gB + (k0), dB);                                    \
  }

#define FT_COMPUTE(buf)                                                      \
  {                                                                          \
    const u16* bA = sh + (buf)*4096;                                         \
    const u16* bB = sh + 8192 + (buf)*2048;                                  \
    bfx8 af[4], bfr[2];                                                      \
    _Pragma("unroll") for (int m = 0; m < 4; ++m)                            \
        af[m] = *(const bfx8*)&bA[(wr * 64 + m * 16 + l16) * 32 + rot];      \
    _Pragma("unroll") for (int n = 0; n < 2; ++n)                            \
        bfr[n] = *(const bfx8*)&bB[(wc * 32 + n * 16 + l16) * 32 + rot];     \
    __builtin_amdgcn_s_setprio(1);                                           \
    _Pragma("unroll") for (int m = 0; m < 4; ++m)                            \
        _Pragma("unroll") for (int n = 0; n < 2; ++n)                        \
            acc[m][n] = __builtin_amdgcn_mfma_f32_16x16x32_bf16(             \
                af[m], bfr[n], acc[m][n], 0, 0, 0);                          \
    __builtin_amdgcn_s_setprio(0);                                           \
  }

  FT_STAGE(0, 0);
#pragma unroll 2
  for (int t = 1; t < 32; ++t) {
    FT_STAGE(t * 32, t & 1);
    asm volatile("s_waitcnt vmcnt(3)" ::: "memory");
    __builtin_amdgcn_s_barrier();
    FT_COMPUTE((t - 1) & 1);
    __builtin_amdgcn_s_barrier();
  }
  asm volatile("s_waitcnt vmcnt(0)" ::: "memory");
  __builtin_amdgcn_s_barrier();
  FT_COMPUTE(1);

  const float* D = dof >= 0 ? (const float*)(base + dof) : nullptr;
  float* F  = fo  >= 0 ? (float*)(base + fo)  : nullptr;
  u16* Ta   = tao >= 0 ? (u16*)(base + tao)   : nullptr;
  u16* Tv   = tvo >= 0 ? (u16*)(base + tvo)   : nullptr;

  float ps[2] = {0.f, 0.f};
  float pr[2] = {0.f, 0.f};

#pragma unroll
  for (int m = 0; m < 4; ++m) {
    int row0 = bm + wr * 64 + m * 16 + lk * 4;
#pragma unroll
    for (int n = 0; n < 2; ++n) {
      int col = wc * 32 + n * 16 + l16;
      float v0 = acc[m][n][0], v1 = acc[m][n][1], v2 = acc[m][n][2], v3 = acc[m][n][3];
      float w0 = v0, w1 = v1, w2 = v2, w3 = v3;
      if (D) {
        w0 = v0 - D[(size_t)(row0 + 0) * FF + col];
        w1 = v1 - D[(size_t)(row0 + 1) * FF + col];
        w2 = v2 - D[(size_t)(row0 + 2) * FF + col];
        w3 = v3 - D[(size_t)(row0 + 3) * FF + col];
      }
      float a0 = fabsf(w0), a1 = fabsf(w1), a2 = fabsf(w2), a3 = fabsf(w3);
      if (pk >= 0) ps[n] += a0 + a1 + a2 + a3;
      if (na.rawK >= 0) pr[n] += v0 + v1 + v2 + v3;
      if (F) {
        F[(size_t)(row0 + 0) * FF + col] = v0;
        F[(size_t)(row0 + 1) * FF + col] = v1;
        F[(size_t)(row0 + 2) * FF + col] = v2;
        F[(size_t)(row0 + 3) * FF + col] = v3;
      }
      if (Ta) {
        u16x4 pkk = {f2b(a0), f2b(a1), f2b(a2), f2b(a3)};
        *(u16x4*)&Ta[(size_t)col * NN + row0] = pkk;
      }
      if (Tv) {
        u16x4 pkk = {f2b(v0), f2b(v1), f2b(v2), f2b(v3)};
        *(u16x4*)&Tv[(size_t)col * NN + row0] = pkk;
      }
    }
  }

  if (pk >= 0) {
#pragma unroll
    for (int n = 0; n < 2; ++n) {
      float v = ps[n];
      v += __shfl_xor(v, 16);
      v += __shfl_xor(v, 32);
      if (lane < 16)
        atomicAdd(&pooled[poolBase + pk * FF + wc * 32 + n * 16 + lane], v);
    }
  }
  if (na.rawK >= 0) {
#pragma unroll
    for (int n = 0; n < 2; ++n) {
      float v = pr[n];
      v += __shfl_xor(v, 16);
      v += __shfl_xor(v, 32);
      if (lane < 16)
        atomicAdd(&pooled[poolBase + na.rawK * FF + wc * 32 + n * 16 + lane], v);
    }
  }
}

__global__ void k_final(const float* __restrict__ pooled, const float* __restrict__ msum,
                        float* __restrict__ out, int total) {
  int i = blockIdx.x * 256 + threadIdx.x;
  if (i < total) out[i] = pooled[i] / msum[i / (KFEAT * FF)];
}

static inline NA mkNA(int a, int nsub, int rawK,
                      int bt0, int bt1, int bt2, int d0, int d1, int d2,
                      int pk0, int pk1, int pk2, int f0, int f1, int f2,
                      int ta0, int ta1, int ta2, int tv0, int tv1, int tv2) {
  NA x;
  x.a = a; x.nsub = nsub; x.rawK = rawK;
  x.bt0 = bt0; x.bt1 = bt1; x.bt2 = bt2;
  x.d0 = d0; x.d1 = d1; x.d2 = d2;
  x.pk0 = pk0; x.pk1 = pk1; x.pk2 = pk2;
  x.f0 = f0; x.f1 = f1; x.f2 = f2;
  x.ta0 = ta0; x.ta1 = ta1; x.ta2 = ta2;
  x.tv0 = tv0; x.tv1 = tv1; x.tv2 = tv2;
  return x;
}

extern "C" void kernel_launch(void* const* d_in, const int* in_sizes, int n_in,
                              void* d_out, int out_size, void* d_ws, size_t ws_size,
                              hipStream_t stream) {
  const float* P = (const float*)d_in[0];
  const float* X = (const float*)d_in[1];
  const float* mask = (const float*)d_in[2];
  float* out = (float*)d_out;
  char* ws = (char*)d_ws;
  float* pooled = (float*)ws;
  float* msum = (float*)(ws + MSUM_OFF);

  hipMemsetAsync(pooled, 0, POOL_BYTES, stream);
  k_msum<<<NSLICE, 256, 0, stream>>>(mask, msum);

  int S = 1;
  if (ws_size > SLICE0 + PS_BYTES) S = (int)((ws_size - SLICE0) / PS_BYTES);
  if (S > NSLICE) S = NSLICE;
  if (S < 1) S = 1;

  for (int b0 = 0; b0 < NSLICE; b0 += S) {
    int n = (NSLICE - b0 < S) ? (NSLICE - b0) : S;
    k_convP<<<dim3(16, 16, n), 256, 0, stream>>>(P, ws, b0);
    k_convX<<<dim3(16, 1, n), 256, 0, stream>>>(X, ws, b0);
    // P2 = P@P (+P2^T), P4 = P2@P2
    k_square<<<64 * n, 256, 0, stream>>>(ws, OFF_P, OFF_PT, OFF_P2, (int)OFF_P2T);
    k_square<<<64 * n, 256, 0, stream>>>(ws, OFF_P2, OFF_P2T, OFF_P4, -1);
    // Y1 = P X
    NA a1 = mkNA(OFF_P, 1, -1, OFF_XT, -1, -1, -1, -1, -1, -1, -1, -1,
                 OFF_Y1, -1, -1, -1, -1, -1, -1, -1, -1);
    k_nar<<<8 * n, 256, 0, stream>>>(ws, b0, pooled, a1);
    // Y2 = P2 X ; s0 = |Y2-Y1| pool k=1
    NA a2 = mkNA(OFF_P2, 1, -1, OFF_XT, -1, -1, (int)OFF_Y1, -1, -1, 1, -1, -1,
                 OFF_Y2, -1, -1, -1, -1, -1, -1, -1, -1);
    k_nar<<<8 * n, 256, 0, stream>>>(ws, b0, pooled, a2);
    // Y4 = P4 X ; s1 = |Y4-Y2| pool k=2, s1T ; Y4 f32 + Y4T
    NA a3 = mkNA(OFF_P4, 1, -1, OFF_XT, -1, -1, (int)OFF_Y2, -1, -1, 2, -1, -1,
                 OFF_Y4, -1, -1, OFF_S1T, -1, -1, OFF_Y4T, -1, -1);
    k_nar<<<8 * n, 256, 0, stream>>>(ws, b0, pooled, a3);
    // Y8 = P4 Y4 ; s2 = |Y8-Y4| pool k=3, s2T ; Y8 f32 + Y8T
    NA a4 = mkNA(OFF_P4, 1, -1, OFF_Y4T, -1, -1, (int)OFF_Y4, -1, -1, 3, -1, -1,
                 OFF_Y8, -1, -1, OFF_S2T, -1, -1, OFF_Y8T, -1, -1);
    k_nar<<<8 * n, 256, 0, stream>>>(ws, b0, pooled, a4);
    // Y12 = P4 Y8 -> Y12T
    NA a5 = mkNA(OFF_P4, 1, -1, OFF_Y8T, -1, -1, -1, -1, -1, -1, -1, -1,
                 -1, -1, -1, -1, -1, -1, OFF_Y12T, -1, -1);
    k_nar<<<8 * n, 256, 0, stream>>>(ws, b0, pooled, a5);
    // Y16 = P4 Y12 ; s3 = |Y16-Y8| pool k=4, s3T ; F0 raw pool k=0
    NA a6 = mkNA(OFF_P4, 1, 0, OFF_Y12T, -1, -1, (int)OFF_Y8, -1, -1, 4, -1, -1,
                 -1, -1, -1, OFF_S3T, -1, -1, -1, -1, -1);
    k_nar<<<8 * n, 256, 0, stream>>>(ws, b0, pooled, a6);
    // P*{s1,s2,s3} -> f32
    NA a7 = mkNA(OFF_P, 3, -1, OFF_S1T, OFF_S2T, OFF_S3T, -1, -1, -1,
                 -1, -1, -1, OFF_PS1, OFF_PS2, OFF_PS3,
                 -1, -1, -1, -1, -1, -1);
    k_nar<<<24 * n, 256, 0, stream>>>(ws, b0, pooled, a7);
    // P2*{s1,s2,s3} ; |psi0 s_i| pools k=5,6,8 ; keep f32 for psi1
    NA a8 = mkNA(OFF_P2, 3, -1, OFF_S1T, OFF_S2T, OFF_S3T,
                 (int)OFF_PS1, (int)OFF_PS2, (int)OFF_PS3, 5, 6, 8,
                 OFF_QS1, OFF_QS2, OFF_QS3, -1, -1, -1, -1, -1, -1);
    k_nar<<<24 * n, 256, 0, stream>>>(ws, b0, pooled, a8);
    // P4*{s2,s3} ; |psi1 s_i| pools k=7,9 ; W = P4 s3 (f32 + WT)
    NA a9 = mkNA(OFF_P4, 2, -1, OFF_S2T, OFF_S3T, -1,
                 (int)OFF_QS2, (int)OFF_QS3, -1, 7, 9, -1,
                 -1, OFF_W, -1, -1, -1, -1, -1, OFF_WT, -1);
    k_nar<<<16 * n, 256, 0, stream>>>(ws, b0, pooled, a9);
    // P4*W ; |psi2 s3| pool k=10
    NA a10 = mkNA(OFF_P4, 1, -1, OFF_WT, -1, -1, (int)OFF_W, -1, -1, 10, -1, -1,
                  -1, -1, -1, -1, -1, -1, -1, -1, -1);
    k_nar<<<8 * n, 256, 0, stream>>>(ws, b0, pooled, a10);
  }
  int total = NSLICE * KFEAT * FF;
  k_final<<<(total + 255) / 256, 256, 0, stream>>>(pooled, msum, out, total);
}